// Round 1
// baseline (745.167 us; speedup 1.0000x reference)
//
#include <hip/hip_runtime.h>
#include <math.h>

constexpr int NB = 16, TSZ = 512, DDIM = 192, NCO = 8, TMM = 1000;

// workspace layout (float indices)
constexpr int WS_SK  = 0;
constexpr int WS_EK  = WS_SK  + NB*TSZ;
constexpr int WS_VW1 = WS_EK  + NB*TSZ;
constexpr int WS_VC1 = WS_VW1 + NB*TSZ*4;
constexpr int WS_BC  = WS_VC1 + NB*TSZ*2;
constexpr int WS_UP  = WS_BC  + NB*TMM*8;
constexpr int WS_AT  = WS_UP  + NB*TMM*DDIM;
constexpr int WS_ML  = WS_AT  + NB*4*TMM*DDIM;   // NB ints live here

// output layout (float indices), tuple concat: out, ~mel_mask, mel_len, Wp, C
constexpr int OUT_OUT  = 0;
constexpr int OUT_MASK = NB*TMM*2*DDIM;            // 6,144,000
constexpr int OUT_MEL  = OUT_MASK + NB*TMM;        // 6,160,000
constexpr int OUT_WP   = OUT_MEL + NB;             // 6,160,016
constexpr int OUT_C    = OUT_WP + NB*4*TMM*TSZ;    // 38,928,016

__device__ __forceinline__ float siluf(float x){ return x / (1.f + expf(-x)); }

// ---------------- K0: cumsum, mel_len, masks ----------------
__global__ __launch_bounds__(TSZ) void k0_scan(const float* __restrict__ dur,
                                               float* __restrict__ ws,
                                               float* __restrict__ out){
    int b = blockIdx.x, tid = threadIdx.x;
    __shared__ float buf[TSZ];
    __shared__ int smel;
    float d = dur[b*TSZ + tid];
    buf[tid] = d;
    __syncthreads();
    for (int off = 1; off < TSZ; off <<= 1){
        float v = (tid >= off) ? buf[tid - off] : 0.f;
        __syncthreads();
        buf[tid] += v;
        __syncthreads();
    }
    float ek = buf[tid];
    ws[WS_EK + b*TSZ + tid] = ek;
    ws[WS_SK + b*TSZ + tid] = ek - d;
    if (tid == 0){
        float tot = buf[TSZ-1];
        int mel = (int)rintf(tot);
        if (mel > TMM) mel = TMM;
        smel = mel;
        ((int*)(ws + WS_ML))[b] = mel;
        out[OUT_MEL + b] = (float)mel;
    }
    __syncthreads();
    int mel = smel;
    for (int t = tid; t < TMM; t += TSZ)
        out[OUT_MASK + b*TMM + t] = (t < mel) ? 1.f : 0.f;
}

// ---------------- K1: conv blocks + W1 pre-fold ----------------
__global__ __launch_bounds__(256) void k1_conv(const float* __restrict__ tokens,
    const float* __restrict__ cwk, const float* __restrict__ cwb,
    const float* __restrict__ cwg, const float* __restrict__ cwbe,
    const float* __restrict__ cwm, const float* __restrict__ cwv,
    const float* __restrict__ cwlg, const float* __restrict__ cwlb,
    const float* __restrict__ cck, const float* __restrict__ ccb,
    const float* __restrict__ ccg, const float* __restrict__ ccbe,
    const float* __restrict__ ccm, const float* __restrict__ ccv,
    const float* __restrict__ cclg, const float* __restrict__ cclb,
    const float* __restrict__ swW1, const float* __restrict__ swb1,
    const float* __restrict__ scW1, const float* __restrict__ scb1,
    float* __restrict__ ws){
    int b = blockIdx.y, s0 = blockIdx.x * 32;
    __shared__ float xt[34*DDIM];
    for (int idx = threadIdx.x; idx < 34*DDIM; idx += 256){
        int r = idx / DDIM, i = idx % DDIM;
        int s = s0 + r - 1;
        xt[idx] = (s >= 0 && s < TSZ) ? tokens[(b*TSZ + s)*DDIM + i] : 0.f;
    }
    __syncthreads();
    int sl = threadIdx.x >> 3, c = threadIdx.x & 7;
    float yw = cwb[c], yc = ccb[c];
    for (int k = 0; k < 3; k++){
        const float* xr = &xt[(sl + k)*DDIM];
        for (int i = 0; i < DDIM; i++){
            float xv = xr[i];
            yw += xv * cwk[(k*DDIM + i)*NCO + c];
            yc += xv * cck[(k*DDIM + i)*NCO + c];
        }
    }
    yw = (yw - cwm[c]) * rsqrtf(cwv[c] + 1e-5f) * cwg[c] + cwbe[c];
    yc = (yc - ccm[c]) * rsqrtf(ccv[c] + 1e-5f) * ccg[c] + ccbe[c];
    yw = siluf(yw);
    yc = siluf(yc);
    __shared__ float vwb[32][NCO], vcb[32][NCO];
    vwb[sl][c] = yw; vcb[sl][c] = yc;
    __syncthreads();
    float mw = 0.f, mc = 0.f;
    for (int j = 0; j < NCO; j++){ mw += vwb[sl][j]; mc += vcb[sl][j]; }
    mw *= (1.f/NCO); mc *= (1.f/NCO);
    float vw_ = 0.f, vc_ = 0.f;
    for (int j = 0; j < NCO; j++){
        float a = vwb[sl][j] - mw; vw_ += a*a;
        float e = vcb[sl][j] - mc; vc_ += e*e;
    }
    vw_ *= (1.f/NCO); vc_ *= (1.f/NCO);
    float lnw = (yw - mw) * rsqrtf(vw_ + 1e-5f) * cwlg[c] + cwlb[c];
    float lnc = (yc - mc) * rsqrtf(vc_ + 1e-5f) * cclg[c] + cclb[c];
    __syncthreads();
    vwb[sl][c] = lnw; vcb[sl][c] = lnc;
    __syncthreads();
    if (threadIdx.x < 32*4){
        int sl2 = threadIdx.x >> 2, j = threadIdx.x & 3;
        float acc = swb1[j];
        for (int cc2 = 0; cc2 < NCO; cc2++) acc += vwb[sl2][cc2] * swW1[(2+cc2)*4 + j];
        ws[WS_VW1 + (b*TSZ + s0 + sl2)*4 + j] = acc;
    }
    if (threadIdx.x < 32*2){
        int sl2 = threadIdx.x >> 1, j = threadIdx.x & 1;
        float acc = scb1[j];
        for (int cc2 = 0; cc2 < NCO; cc2++) acc += vcb[sl2][cc2] * scW1[(2+cc2)*2 + j];
        ws[WS_VC1 + (b*TSZ + s0 + sl2)*2 + j] = acc;
    }
}

// ---------------- K2: S/E + MLPs + softmax + Wp,C,Bc ----------------
__global__ __launch_bounds__(TSZ) void k2_swish(const int* __restrict__ src_len,
    const float* __restrict__ swW1, const float* __restrict__ swW2,
    const float* __restrict__ swb2, const float* __restrict__ swW3,
    const float* __restrict__ swb3,
    const float* __restrict__ scW1, const float* __restrict__ scW2,
    const float* __restrict__ scb2, const float* __restrict__ scW3,
    const float* __restrict__ scb3,
    float* __restrict__ ws, float* __restrict__ out){
    int t = blockIdx.x, b = blockIdx.y, s = threadIdx.x;
    int mel = ((const int*)(ws + WS_ML))[b];
    int slen = src_len[b];
    bool smask = (s >= slen);
    bool am = smask || (t >= mel);
    float sk = ws[WS_SK + b*TSZ + s];
    float ek = ws[WS_EK + b*TSZ + s];
    float tv = (float)(t + 1);
    float Sv = am ? 0.f : (tv - sk);
    float Ev = am ? 0.f : (ek - tv);
    float4 vw1 = *(const float4*)&ws[WS_VW1 + (b*TSZ + s)*4];
    float2 vc1 = *(const float2*)&ws[WS_VC1 + (b*TSZ + s)*2];

    // W-MLP (DW=4)
    float h1[4], h2[4], wr[4];
    const float* vw1p = (const float*)&vw1;
    #pragma unroll
    for (int j = 0; j < 4; j++)
        h1[j] = siluf(Sv*swW1[j] + Ev*swW1[4+j] + vw1p[j]);
    #pragma unroll
    for (int j = 0; j < 4; j++){
        float a = swb2[j];
        #pragma unroll
        for (int i = 0; i < 4; i++) a += h1[i]*swW2[i*4 + j];
        h2[j] = siluf(a);
    }
    #pragma unroll
    for (int q = 0; q < 4; q++){
        float a = swb3[q];
        #pragma unroll
        for (int i = 0; i < 4; i++) a += h2[i]*swW3[i*4 + q];
        wr[q] = a;
    }
    if (smask){ wr[0] = wr[1] = wr[2] = wr[3] = -INFINITY; }

    // C-MLP (DC=2)
    float c1[2], c2[2], ccv2[2];
    const float* vc1p = (const float*)&vc1;
    #pragma unroll
    for (int j = 0; j < 2; j++)
        c1[j] = siluf(Sv*scW1[j] + Ev*scW1[2+j] + vc1p[j]);
    #pragma unroll
    for (int j = 0; j < 2; j++){
        float a = scb2[j];
        #pragma unroll
        for (int i = 0; i < 2; i++) a += c1[i]*scW2[i*2 + j];
        c2[j] = siluf(a);
    }
    #pragma unroll
    for (int p = 0; p < 2; p++){
        float a = scb3[p];
        #pragma unroll
        for (int i = 0; i < 2; i++) a += c2[i]*scW3[i*2 + p];
        ccv2[p] = a;
    }
    // write C (always computed, even masked positions: S=E=0 there)
    *(float2*)&out[OUT_C + ((b*TMM + t)*TSZ + s)*2] = make_float2(ccv2[0], ccv2[1]);

    // softmax over s per q
    int lane = s & 63, wid = s >> 6;
    __shared__ float red[4][8];
    float m[4], p4[4], w4[4];
    #pragma unroll
    for (int q = 0; q < 4; q++){
        float v = wr[q];
        for (int o = 32; o; o >>= 1) v = fmaxf(v, __shfl_down(v, o));
        if (lane == 0) red[q][wid] = v;
    }
    __syncthreads();
    if (s < 4){
        float v = red[s][0];
        for (int w = 1; w < 8; w++) v = fmaxf(v, red[s][w]);
        red[s][0] = v;
    }
    __syncthreads();
    #pragma unroll
    for (int q = 0; q < 4; q++) m[q] = red[q][0];
    __syncthreads();
    #pragma unroll
    for (int q = 0; q < 4; q++){
        p4[q] = expf(wr[q] - m[q]);   // masked lanes: exp(-inf) = 0
        float v = p4[q];
        for (int o = 32; o; o >>= 1) v += __shfl_down(v, o);
        if (lane == 0) red[q][wid] = v;
    }
    __syncthreads();
    if (s < 4){
        float v = 0.f;
        for (int w = 0; w < 8; w++) v += red[s][w];
        red[s][0] = v;
    }
    __syncthreads();
    #pragma unroll
    for (int q = 0; q < 4; q++)
        w4[q] = (t < mel) ? (p4[q] / red[q][0]) : 0.f;

    #pragma unroll
    for (int q = 0; q < 4; q++)
        out[OUT_WP + ((b*4 + q)*TMM + t)*TSZ + s] = w4[q];

    // Bc[b,t,j] = sum_s w4[q]*C[s,p], j=q*2+p
    float bc[8];
    #pragma unroll
    for (int q = 0; q < 4; q++)
        #pragma unroll
        for (int p = 0; p < 2; p++) bc[q*2 + p] = w4[q]*ccv2[p];
    __shared__ float redb[8][8];
    #pragma unroll
    for (int j = 0; j < 8; j++){
        float v = bc[j];
        for (int o = 32; o; o >>= 1) v += __shfl_down(v, o);
        bc[j] = v;
    }
    if (lane == 0)
        #pragma unroll
        for (int j = 0; j < 8; j++) redb[wid][j] = bc[j];
    __syncthreads();
    if (s < 8){
        float v = 0.f;
        for (int w = 0; w < 8; w++) v += redb[w][s];
        ws[WS_BC + (b*TMM + t)*8 + s] = v;
    }
}

// ---------------- K3: Atmp[b,q,t,h] = sum_s Wp[b,q,t,s] * tok[b,s,h] ----------------
__global__ __launch_bounds__(256) void k3_gemm1(const float* __restrict__ out,
                                                const float* __restrict__ tokens,
                                                float* __restrict__ ws){
    int bq = blockIdx.z;
    int t0 = blockIdx.x * 64;
    int h0 = blockIdx.y * 64;
    int b = bq >> 2;
    const float* Wp = out + OUT_WP + (size_t)bq*TMM*TSZ;
    __shared__ __align__(16) float Asm[32][68];
    __shared__ __align__(16) float Bsm[32][68];
    int tid = threadIdx.x;
    int ty = tid >> 4, tx = tid & 15;
    float acc[4][4] = {};
    for (int s0 = 0; s0 < TSZ; s0 += 32){
        #pragma unroll
        for (int l = 0; l < 2; l++){
            int idx = tid + l*256;
            int r = idx >> 3, c4 = idx & 7;
            int t = t0 + r;
            float4 v = make_float4(0.f, 0.f, 0.f, 0.f);
            if (t < TMM) v = *(const float4*)&Wp[t*TSZ + s0 + c4*4];
            Asm[c4*4+0][r] = v.x; Asm[c4*4+1][r] = v.y;
            Asm[c4*4+2][r] = v.z; Asm[c4*4+3][r] = v.w;
        }
        #pragma unroll
        for (int l = 0; l < 2; l++){
            int idx = tid + l*256;
            int r = idx >> 4, c4 = idx & 15;
            *(float4*)&Bsm[r][c4*4] =
                *(const float4*)&tokens[(b*TSZ + s0 + r)*DDIM + h0 + c4*4];
        }
        __syncthreads();
        #pragma unroll
        for (int k = 0; k < 32; k++){
            float4 a = *(float4*)&Asm[k][ty*4];
            float4 bb = *(float4*)&Bsm[k][tx*4];
            acc[0][0] += a.x*bb.x; acc[0][1] += a.x*bb.y; acc[0][2] += a.x*bb.z; acc[0][3] += a.x*bb.w;
            acc[1][0] += a.y*bb.x; acc[1][1] += a.y*bb.y; acc[1][2] += a.y*bb.z; acc[1][3] += a.y*bb.w;
            acc[2][0] += a.z*bb.x; acc[2][1] += a.z*bb.y; acc[2][2] += a.z*bb.z; acc[2][3] += a.z*bb.w;
            acc[3][0] += a.w*bb.x; acc[3][1] += a.w*bb.y; acc[3][2] += a.w*bb.z; acc[3][3] += a.w*bb.w;
        }
        __syncthreads();
    }
    #pragma unroll
    for (int r = 0; r < 4; r++){
        int t = t0 + ty*4 + r;
        if (t < TMM)
            *(float4*)&ws[WS_AT + ((size_t)bq*TMM + t)*DDIM + h0 + tx*4] =
                make_float4(acc[r][0], acc[r][1], acc[r][2], acc[r][3]);
    }
}

// ---------------- K4: up_pre = Atmp @ lw_W + lw_b + Bc @ le_W ----------------
__global__ __launch_bounds__(256) void k4_gemm2(const float* __restrict__ lwW,
                                                const float* __restrict__ lwb,
                                                const float* __restrict__ leW,
                                                float* __restrict__ ws){
    int b = blockIdx.z;
    int t0 = blockIdx.x * 64;
    int d0 = blockIdx.y * 64;
    __shared__ __align__(16) float Asm[32][68];
    __shared__ __align__(16) float Lsm[32][68];
    int tid = threadIdx.x;
    int ty = tid >> 4, tx = tid & 15;
    float acc[4][4] = {};
    for (int kc = 0; kc < 24; kc++){
        int q = kc / 6, hh0 = (kc % 6) * 32;
        #pragma unroll
        for (int l = 0; l < 2; l++){
            int idx = tid + l*256;
            int r = idx >> 3, c4 = idx & 7;
            int t = t0 + r;
            float4 v = make_float4(0.f, 0.f, 0.f, 0.f);
            if (t < TMM)
                v = *(const float4*)&ws[WS_AT + ((size_t)(b*4 + q)*TMM + t)*DDIM + hh0 + c4*4];
            Asm[c4*4+0][r] = v.x; Asm[c4*4+1][r] = v.y;
            Asm[c4*4+2][r] = v.z; Asm[c4*4+3][r] = v.w;
        }
        #pragma unroll
        for (int l = 0; l < 2; l++){
            int idx = tid + l*256;
            int r = idx >> 4, c4 = idx & 15;
            *(float4*)&Lsm[r][c4*4] =
                *(const float4*)&lwW[(q*DDIM + hh0 + r)*DDIM + d0 + c4*4];
        }
        __syncthreads();
        #pragma unroll
        for (int k = 0; k < 32; k++){
            float4 a = *(float4*)&Asm[k][ty*4];
            float4 bb = *(float4*)&Lsm[k][tx*4];
            acc[0][0] += a.x*bb.x; acc[0][1] += a.x*bb.y; acc[0][2] += a.x*bb.z; acc[0][3] += a.x*bb.w;
            acc[1][0] += a.y*bb.x; acc[1][1] += a.y*bb.y; acc[1][2] += a.y*bb.z; acc[1][3] += a.y*bb.w;
            acc[2][0] += a.z*bb.x; acc[2][1] += a.z*bb.y; acc[2][2] += a.z*bb.z; acc[2][3] += a.z*bb.w;
            acc[3][0] += a.w*bb.x; acc[3][1] += a.w*bb.y; acc[3][2] += a.w*bb.z; acc[3][3] += a.w*bb.w;
        }
        __syncthreads();
    }
    #pragma unroll
    for (int r = 0; r < 4; r++){
        int t = t0 + ty*4 + r;
        if (t < TMM){
            float bcv[8];
            #pragma unroll
            for (int j = 0; j < 8; j++) bcv[j] = ws[WS_BC + (b*TMM + t)*8 + j];
            float res[4];
            #pragma unroll
            for (int cix = 0; cix < 4; cix++){
                int d = d0 + tx*4 + cix;
                float a = acc[r][cix] + lwb[d];
                #pragma unroll
                for (int j = 0; j < 8; j++) a += bcv[j]*leW[j*DDIM + d];
                res[cix] = a;
            }
            *(float4*)&ws[WS_UP + ((size_t)b*TMM + t)*DDIM + d0 + tx*4] =
                make_float4(res[0], res[1], res[2], res[3]);
        }
    }
}

// ---------------- K5: LayerNorm + @po_W + mel-mask ----------------
__global__ __launch_bounds__(384) void k5_out(const float* __restrict__ lng,
                                              const float* __restrict__ lnb,
                                              const float* __restrict__ poW,
                                              const float* __restrict__ ws,
                                              float* __restrict__ out){
    int b = blockIdx.y, t0 = blockIdx.x * 16;
    int mel = ((const int*)(ws + WS_ML))[b];
    __shared__ float upl[16*DDIM];
    __shared__ float mrow[16], rrow[16];
    for (int idx = threadIdx.x; idx < 16*DDIM; idx += 384){
        int r = idx / DDIM, cix = idx % DDIM;
        int t = t0 + r;
        upl[idx] = (t < TMM) ? ws[WS_UP + ((size_t)b*TMM + t)*DDIM + cix] : 0.f;
    }
    __syncthreads();
    if (threadIdx.x < 16){
        int r = threadIdx.x;
        float s = 0.f;
        for (int c = 0; c < DDIM; c++) s += upl[r*DDIM + c];
        float m = s * (1.f/DDIM);
        float v = 0.f;
        for (int c = 0; c < DDIM; c++){ float a = upl[r*DDIM + c] - m; v += a*a; }
        v *= (1.f/DDIM);
        mrow[r] = m; rrow[r] = rsqrtf(v + 1e-5f);
    }
    __syncthreads();
    for (int idx = threadIdx.x; idx < 16*DDIM; idx += 384){
        int r = idx / DDIM, cix = idx % DDIM;
        upl[idx] = (upl[idx] - mrow[r]) * rrow[r] * lng[cix] + lnb[cix];
    }
    __syncthreads();
    int j = threadIdx.x;  // 0..383
    float acc[16] = {};
    for (int k = 0; k < DDIM; k++){
        float po = poW[k*384 + j];
        #pragma unroll
        for (int r = 0; r < 16; r++) acc[r] += upl[r*DDIM + k] * po;
    }
    #pragma unroll
    for (int r = 0; r < 16; r++){
        int t = t0 + r;
        if (t < TMM)
            out[OUT_OUT + ((size_t)b*TMM + t)*384 + j] = (t < mel) ? acc[r] : 0.f;
    }
}

extern "C" void kernel_launch(void* const* d_in, const int* in_sizes, int n_in,
                              void* d_out, int out_size, void* d_ws, size_t ws_size,
                              hipStream_t stream){
    const float* duration  = (const float*)d_in[0];
    const float* tokens    = (const float*)d_in[1];
    const int*   src_len   = (const int*)d_in[2];
    // d_in[3] src_mask, d_in[4] tgt_len, d_in[5] max_src_len: recomputed/unused
    const float* cw_kernel = (const float*)d_in[6];
    const float* cw_bias   = (const float*)d_in[7];
    const float* cw_bng    = (const float*)d_in[8];
    const float* cw_bnb    = (const float*)d_in[9];
    const float* cw_bnm    = (const float*)d_in[10];
    const float* cw_bnv    = (const float*)d_in[11];
    const float* cw_lng    = (const float*)d_in[12];
    const float* cw_lnb    = (const float*)d_in[13];
    const float* sw_W1     = (const float*)d_in[14];
    const float* sw_b1     = (const float*)d_in[15];
    const float* sw_W2     = (const float*)d_in[16];
    const float* sw_b2     = (const float*)d_in[17];
    const float* sw_W3     = (const float*)d_in[18];
    const float* sw_b3     = (const float*)d_in[19];
    const float* lw_W      = (const float*)d_in[20];
    const float* lw_b      = (const float*)d_in[21];
    const float* cc_kernel = (const float*)d_in[22];
    const float* cc_bias   = (const float*)d_in[23];
    const float* cc_bng    = (const float*)d_in[24];
    const float* cc_bnb    = (const float*)d_in[25];
    const float* cc_bnm    = (const float*)d_in[26];
    const float* cc_bnv    = (const float*)d_in[27];
    const float* cc_lng    = (const float*)d_in[28];
    const float* cc_lnb    = (const float*)d_in[29];
    const float* sc_W1     = (const float*)d_in[30];
    const float* sc_b1     = (const float*)d_in[31];
    const float* sc_W2     = (const float*)d_in[32];
    const float* sc_b2     = (const float*)d_in[33];
    const float* sc_W3     = (const float*)d_in[34];
    const float* sc_b3     = (const float*)d_in[35];
    const float* le_W      = (const float*)d_in[36];
    const float* ln_gamma  = (const float*)d_in[37];
    const float* ln_beta   = (const float*)d_in[38];
    const float* po_W      = (const float*)d_in[39];
    float* out = (float*)d_out;
    float* ws  = (float*)d_ws;

    k0_scan<<<NB, TSZ, 0, stream>>>(duration, ws, out);
    k1_conv<<<dim3(16, NB), 256, 0, stream>>>(tokens,
        cw_kernel, cw_bias, cw_bng, cw_bnb, cw_bnm, cw_bnv, cw_lng, cw_lnb,
        cc_kernel, cc_bias, cc_bng, cc_bnb, cc_bnm, cc_bnv, cc_lng, cc_lnb,
        sw_W1, sw_b1, sc_W1, sc_b1, ws);
    k2_swish<<<dim3(TMM, NB), TSZ, 0, stream>>>(src_len,
        sw_W1, sw_W2, sw_b2, sw_W3, sw_b3,
        sc_W1, sc_W2, sc_b2, sc_W3, sc_b3, ws, out);
    k3_gemm1<<<dim3(16, 3, NB*4), 256, 0, stream>>>(out, tokens, ws);
    k4_gemm2<<<dim3(16, 3, NB), 256, 0, stream>>>(lw_W, lw_b, le_W, ws);
    k5_out<<<dim3(63, NB), 384, 0, stream>>>(ln_gamma, ln_beta, po_W, ws, out);
}

// Round 2
// 701.039 us; speedup vs baseline: 1.0629x; 1.0629x over previous
//
#include <hip/hip_runtime.h>
#include <math.h>

constexpr int NB = 16, TSZ = 512, DDIM = 192, NCO = 8, TMM = 1000;

// workspace layout (float indices)
constexpr int WS_SK  = 0;
constexpr int WS_EK  = WS_SK  + NB*TSZ;
constexpr int WS_VW1 = WS_EK  + NB*TSZ;
constexpr int WS_VC1 = WS_VW1 + NB*TSZ*4;
constexpr int WS_BC  = WS_VC1 + NB*TSZ*2;
constexpr int WS_UP  = WS_BC  + NB*TMM*8;
constexpr int WS_AT  = WS_UP  + NB*TMM*DDIM;
constexpr int WS_ML  = WS_AT  + NB*4*TMM*DDIM;   // NB ints live here

// output layout (float indices), tuple concat: out, ~mel_mask, mel_len, Wp, C
constexpr int OUT_OUT  = 0;
constexpr int OUT_MASK = NB*TMM*2*DDIM;            // 6,144,000
constexpr int OUT_MEL  = OUT_MASK + NB*TMM;        // 6,160,000
constexpr int OUT_WP   = OUT_MEL + NB;             // 6,160,016
constexpr int OUT_C    = OUT_WP + NB*4*TMM*TSZ;    // 38,928,016

__device__ __forceinline__ float siluf(float x){ return x / (1.f + expf(-x)); }
__device__ __forceinline__ float silu_fast(float x){
    return x * __builtin_amdgcn_rcpf(1.f + __expf(-x));
}

// ---------------- K0: cumsum, mel_len, masks ----------------
__global__ __launch_bounds__(TSZ) void k0_scan(const float* __restrict__ dur,
                                               float* __restrict__ ws,
                                               float* __restrict__ out){
    int b = blockIdx.x, tid = threadIdx.x;
    __shared__ float buf[TSZ];
    __shared__ int smel;
    float d = dur[b*TSZ + tid];
    buf[tid] = d;
    __syncthreads();
    for (int off = 1; off < TSZ; off <<= 1){
        float v = (tid >= off) ? buf[tid - off] : 0.f;
        __syncthreads();
        buf[tid] += v;
        __syncthreads();
    }
    float ek = buf[tid];
    ws[WS_EK + b*TSZ + tid] = ek;
    ws[WS_SK + b*TSZ + tid] = ek - d;
    if (tid == 0){
        float tot = buf[TSZ-1];
        int mel = (int)rintf(tot);
        if (mel > TMM) mel = TMM;
        smel = mel;
        ((int*)(ws + WS_ML))[b] = mel;
        out[OUT_MEL + b] = (float)mel;
    }
    __syncthreads();
    int mel = smel;
    for (int t = tid; t < TMM; t += TSZ)
        out[OUT_MASK + b*TMM + t] = (t < mel) ? 1.f : 0.f;
}

// ---------------- K1: conv blocks + W1 pre-fold ----------------
__global__ __launch_bounds__(256) void k1_conv(const float* __restrict__ tokens,
    const float* __restrict__ cwk, const float* __restrict__ cwb,
    const float* __restrict__ cwg, const float* __restrict__ cwbe,
    const float* __restrict__ cwm, const float* __restrict__ cwv,
    const float* __restrict__ cwlg, const float* __restrict__ cwlb,
    const float* __restrict__ cck, const float* __restrict__ ccb,
    const float* __restrict__ ccg, const float* __restrict__ ccbe,
    const float* __restrict__ ccm, const float* __restrict__ ccv,
    const float* __restrict__ cclg, const float* __restrict__ cclb,
    const float* __restrict__ swW1, const float* __restrict__ swb1,
    const float* __restrict__ scW1, const float* __restrict__ scb1,
    float* __restrict__ ws){
    int b = blockIdx.y, s0 = blockIdx.x * 32;
    __shared__ float xt[34*DDIM];
    for (int idx = threadIdx.x; idx < 34*DDIM; idx += 256){
        int r = idx / DDIM, i = idx % DDIM;
        int s = s0 + r - 1;
        xt[idx] = (s >= 0 && s < TSZ) ? tokens[(b*TSZ + s)*DDIM + i] : 0.f;
    }
    __syncthreads();
    int sl = threadIdx.x >> 3, c = threadIdx.x & 7;
    float yw = cwb[c], yc = ccb[c];
    for (int k = 0; k < 3; k++){
        const float* xr = &xt[(sl + k)*DDIM];
        for (int i = 0; i < DDIM; i++){
            float xv = xr[i];
            yw += xv * cwk[(k*DDIM + i)*NCO + c];
            yc += xv * cck[(k*DDIM + i)*NCO + c];
        }
    }
    yw = (yw - cwm[c]) * rsqrtf(cwv[c] + 1e-5f) * cwg[c] + cwbe[c];
    yc = (yc - ccm[c]) * rsqrtf(ccv[c] + 1e-5f) * ccg[c] + ccbe[c];
    yw = siluf(yw);
    yc = siluf(yc);
    __shared__ float vwb[32][NCO], vcb[32][NCO];
    vwb[sl][c] = yw; vcb[sl][c] = yc;
    __syncthreads();
    float mw = 0.f, mc = 0.f;
    for (int j = 0; j < NCO; j++){ mw += vwb[sl][j]; mc += vcb[sl][j]; }
    mw *= (1.f/NCO); mc *= (1.f/NCO);
    float vw_ = 0.f, vc_ = 0.f;
    for (int j = 0; j < NCO; j++){
        float a = vwb[sl][j] - mw; vw_ += a*a;
        float e = vcb[sl][j] - mc; vc_ += e*e;
    }
    vw_ *= (1.f/NCO); vc_ *= (1.f/NCO);
    float lnw = (yw - mw) * rsqrtf(vw_ + 1e-5f) * cwlg[c] + cwlb[c];
    float lnc = (yc - mc) * rsqrtf(vc_ + 1e-5f) * cclg[c] + cclb[c];
    __syncthreads();
    vwb[sl][c] = lnw; vcb[sl][c] = lnc;
    __syncthreads();
    if (threadIdx.x < 32*4){
        int sl2 = threadIdx.x >> 2, j = threadIdx.x & 3;
        float acc = swb1[j];
        for (int cc2 = 0; cc2 < NCO; cc2++) acc += vwb[sl2][cc2] * swW1[(2+cc2)*4 + j];
        ws[WS_VW1 + (b*TSZ + s0 + sl2)*4 + j] = acc;
    }
    if (threadIdx.x < 32*2){
        int sl2 = threadIdx.x >> 1, j = threadIdx.x & 1;
        float acc = scb1[j];
        for (int cc2 = 0; cc2 < NCO; cc2++) acc += vcb[sl2][cc2] * scW1[(2+cc2)*2 + j];
        ws[WS_VC1 + (b*TSZ + s0 + sl2)*2 + j] = acc;
    }
}

// ---------------- K2: one wave per (b,t); 8 s-values per lane ----------------
__global__ __launch_bounds__(256) void k2_swish(const int* __restrict__ src_len,
    const float* __restrict__ swW1, const float* __restrict__ swW2,
    const float* __restrict__ swb2, const float* __restrict__ swW3,
    const float* __restrict__ swb3,
    const float* __restrict__ scW1, const float* __restrict__ scW2,
    const float* __restrict__ scb2, const float* __restrict__ scW3,
    const float* __restrict__ scb3,
    float* __restrict__ ws, float* __restrict__ out){
    int wid = threadIdx.x >> 6, lane = threadIdx.x & 63;
    int t = blockIdx.x * 4 + wid;          // grid.x = 250 -> t in [0,1000)
    int b = blockIdx.y;
    int mel = ((const int*)(ws + WS_ML))[b];
    int slen = src_len[b];
    bool tmask = (t >= mel);
    float tv = (float)(t + 1);

    float wr[8][4];     // W-MLP outputs (later overwritten with exp())
    float cv[8][2];     // C-MLP outputs
    float mx[4] = {-1e30f, -1e30f, -1e30f, -1e30f};

    #pragma unroll
    for (int i = 0; i < 8; i++){
        int s = i*64 + lane;
        bool smask = (s >= slen);
        bool am = smask || tmask;
        float sk = ws[WS_SK + b*TSZ + s];
        float ek = ws[WS_EK + b*TSZ + s];
        float Sv = am ? 0.f : (tv - sk);
        float Ev = am ? 0.f : (ek - tv);
        float4 vw1 = *(const float4*)&ws[WS_VW1 + (b*TSZ + s)*4];
        float2 vc1 = *(const float2*)&ws[WS_VC1 + (b*TSZ + s)*2];
        const float* vw1p = (const float*)&vw1;
        const float* vc1p = (const float*)&vc1;

        float h1[4], h2[4];
        #pragma unroll
        for (int j = 0; j < 4; j++)
            h1[j] = silu_fast(Sv*swW1[j] + Ev*swW1[4+j] + vw1p[j]);
        #pragma unroll
        for (int j = 0; j < 4; j++){
            float a = swb2[j];
            #pragma unroll
            for (int u = 0; u < 4; u++) a += h1[u]*swW2[u*4 + j];
            h2[j] = silu_fast(a);
        }
        #pragma unroll
        for (int q = 0; q < 4; q++){
            float a = swb3[q];
            #pragma unroll
            for (int u = 0; u < 4; u++) a += h2[u]*swW3[u*4 + q];
            float v = smask ? -1e30f : a;
            wr[i][q] = v;
            mx[q] = fmaxf(mx[q], v);
        }

        float c1[2], c2[2];
        #pragma unroll
        for (int j = 0; j < 2; j++)
            c1[j] = silu_fast(Sv*scW1[j] + Ev*scW1[2+j] + vc1p[j]);
        #pragma unroll
        for (int j = 0; j < 2; j++){
            float a = scb2[j];
            #pragma unroll
            for (int u = 0; u < 2; u++) a += c1[u]*scW2[u*2 + j];
            c2[j] = silu_fast(a);
        }
        #pragma unroll
        for (int p = 0; p < 2; p++){
            float a = scb3[p];
            #pragma unroll
            for (int u = 0; u < 2; u++) a += c2[u]*scW3[u*2 + p];
            cv[i][p] = a;
        }
        *(float2*)&out[OUT_C + ((size_t)(b*TMM + t)*TSZ + s)*2] =
            make_float2(cv[i][0], cv[i][1]);
    }

    // wave butterfly: max per q
    #pragma unroll
    for (int q = 0; q < 4; q++)
        #pragma unroll
        for (int o = 32; o; o >>= 1)
            mx[q] = fmaxf(mx[q], __shfl_xor(mx[q], o, 64));

    // exp + local sum
    float sum[4] = {0.f, 0.f, 0.f, 0.f};
    #pragma unroll
    for (int i = 0; i < 8; i++)
        #pragma unroll
        for (int q = 0; q < 4; q++){
            float p = __expf(wr[i][q] - mx[q]);
            wr[i][q] = p;
            sum[q] += p;
        }
    #pragma unroll
    for (int q = 0; q < 4; q++)
        #pragma unroll
        for (int o = 32; o; o >>= 1)
            sum[q] += __shfl_xor(sum[q], o, 64);
    float rs[4];
    #pragma unroll
    for (int q = 0; q < 4; q++) rs[q] = __builtin_amdgcn_rcpf(sum[q]);

    // normalize, write Wp, accumulate Bc
    float bc[8] = {0.f,0.f,0.f,0.f,0.f,0.f,0.f,0.f};
    #pragma unroll
    for (int i = 0; i < 8; i++){
        int s = i*64 + lane;
        #pragma unroll
        for (int q = 0; q < 4; q++){
            float w = tmask ? 0.f : wr[i][q]*rs[q];
            out[OUT_WP + ((size_t)(b*4 + q)*TMM + t)*TSZ + s] = w;
            bc[q*2 + 0] += w*cv[i][0];
            bc[q*2 + 1] += w*cv[i][1];
        }
    }
    #pragma unroll
    for (int j = 0; j < 8; j++)
        #pragma unroll
        for (int o = 32; o; o >>= 1)
            bc[j] += __shfl_xor(bc[j], o, 64);
    if (lane == 0){
        *(float4*)&ws[WS_BC + (b*TMM + t)*8 + 0] = make_float4(bc[0], bc[1], bc[2], bc[3]);
        *(float4*)&ws[WS_BC + (b*TMM + t)*8 + 4] = make_float4(bc[4], bc[5], bc[6], bc[7]);
    }
}

// ---------------- K3: Atmp[b,q,t,h] = sum_s Wp[b,q,t,s] * tok[b,s,h] ----------------
__global__ __launch_bounds__(256) void k3_gemm1(const float* __restrict__ out,
                                                const float* __restrict__ tokens,
                                                float* __restrict__ ws){
    int bq = blockIdx.z;
    int t0 = blockIdx.x * 64;
    int h0 = blockIdx.y * 64;
    int b = bq >> 2;
    const float* Wp = out + OUT_WP + (size_t)bq*TMM*TSZ;
    __shared__ __align__(16) float Asm[32][68];
    __shared__ __align__(16) float Bsm[32][68];
    int tid = threadIdx.x;
    int ty = tid >> 4, tx = tid & 15;
    float acc[4][4] = {};
    for (int s0 = 0; s0 < TSZ; s0 += 32){
        #pragma unroll
        for (int l = 0; l < 2; l++){
            int idx = tid + l*256;
            int r = idx >> 3, c4 = idx & 7;
            int t = t0 + r;
            float4 v = make_float4(0.f, 0.f, 0.f, 0.f);
            if (t < TMM) v = *(const float4*)&Wp[t*TSZ + s0 + c4*4];
            Asm[c4*4+0][r] = v.x; Asm[c4*4+1][r] = v.y;
            Asm[c4*4+2][r] = v.z; Asm[c4*4+3][r] = v.w;
        }
        #pragma unroll
        for (int l = 0; l < 2; l++){
            int idx = tid + l*256;
            int r = idx >> 4, c4 = idx & 15;
            *(float4*)&Bsm[r][c4*4] =
                *(const float4*)&tokens[(b*TSZ + s0 + r)*DDIM + h0 + c4*4];
        }
        __syncthreads();
        #pragma unroll
        for (int k = 0; k < 32; k++){
            float4 a = *(float4*)&Asm[k][ty*4];
            float4 bb = *(float4*)&Bsm[k][tx*4];
            acc[0][0] += a.x*bb.x; acc[0][1] += a.x*bb.y; acc[0][2] += a.x*bb.z; acc[0][3] += a.x*bb.w;
            acc[1][0] += a.y*bb.x; acc[1][1] += a.y*bb.y; acc[1][2] += a.y*bb.z; acc[1][3] += a.y*bb.w;
            acc[2][0] += a.z*bb.x; acc[2][1] += a.z*bb.y; acc[2][2] += a.z*bb.z; acc[2][3] += a.z*bb.w;
            acc[3][0] += a.w*bb.x; acc[3][1] += a.w*bb.y; acc[3][2] += a.w*bb.z; acc[3][3] += a.w*bb.w;
        }
        __syncthreads();
    }
    #pragma unroll
    for (int r = 0; r < 4; r++){
        int t = t0 + ty*4 + r;
        if (t < TMM)
            *(float4*)&ws[WS_AT + ((size_t)bq*TMM + t)*DDIM + h0 + tx*4] =
                make_float4(acc[r][0], acc[r][1], acc[r][2], acc[r][3]);
    }
}

// ---------------- K4: up_pre = Atmp @ lw_W + lw_b + Bc @ le_W ----------------
__global__ __launch_bounds__(256) void k4_gemm2(const float* __restrict__ lwW,
                                                const float* __restrict__ lwb,
                                                const float* __restrict__ leW,
                                                float* __restrict__ ws){
    int b = blockIdx.z;
    int t0 = blockIdx.x * 64;
    int d0 = blockIdx.y * 64;
    __shared__ __align__(16) float Asm[32][68];
    __shared__ __align__(16) float Lsm[32][68];
    int tid = threadIdx.x;
    int ty = tid >> 4, tx = tid & 15;
    float acc[4][4] = {};
    for (int kc = 0; kc < 24; kc++){
        int q = kc / 6, hh0 = (kc % 6) * 32;
        #pragma unroll
        for (int l = 0; l < 2; l++){
            int idx = tid + l*256;
            int r = idx >> 3, c4 = idx & 7;
            int t = t0 + r;
            float4 v = make_float4(0.f, 0.f, 0.f, 0.f);
            if (t < TMM)
                v = *(const float4*)&ws[WS_AT + ((size_t)(b*4 + q)*TMM + t)*DDIM + hh0 + c4*4];
            Asm[c4*4+0][r] = v.x; Asm[c4*4+1][r] = v.y;
            Asm[c4*4+2][r] = v.z; Asm[c4*4+3][r] = v.w;
        }
        #pragma unroll
        for (int l = 0; l < 2; l++){
            int idx = tid + l*256;
            int r = idx >> 4, c4 = idx & 15;
            *(float4*)&Lsm[r][c4*4] =
                *(const float4*)&lwW[(q*DDIM + hh0 + r)*DDIM + d0 + c4*4];
        }
        __syncthreads();
        #pragma unroll
        for (int k = 0; k < 32; k++){
            float4 a = *(float4*)&Asm[k][ty*4];
            float4 bb = *(float4*)&Lsm[k][tx*4];
            acc[0][0] += a.x*bb.x; acc[0][1] += a.x*bb.y; acc[0][2] += a.x*bb.z; acc[0][3] += a.x*bb.w;
            acc[1][0] += a.y*bb.x; acc[1][1] += a.y*bb.y; acc[1][2] += a.y*bb.z; acc[1][3] += a.y*bb.w;
            acc[2][0] += a.z*bb.x; acc[2][1] += a.z*bb.y; acc[2][2] += a.z*bb.z; acc[2][3] += a.z*bb.w;
            acc[3][0] += a.w*bb.x; acc[3][1] += a.w*bb.y; acc[3][2] += a.w*bb.z; acc[3][3] += a.w*bb.w;
        }
        __syncthreads();
    }
    #pragma unroll
    for (int r = 0; r < 4; r++){
        int t = t0 + ty*4 + r;
        if (t < TMM){
            float bcv[8];
            #pragma unroll
            for (int j = 0; j < 8; j++) bcv[j] = ws[WS_BC + (b*TMM + t)*8 + j];
            float res[4];
            #pragma unroll
            for (int cix = 0; cix < 4; cix++){
                int d = d0 + tx*4 + cix;
                float a = acc[r][cix] + lwb[d];
                #pragma unroll
                for (int j = 0; j < 8; j++) a += bcv[j]*leW[j*DDIM + d];
                res[cix] = a;
            }
            *(float4*)&ws[WS_UP + ((size_t)b*TMM + t)*DDIM + d0 + tx*4] =
                make_float4(res[0], res[1], res[2], res[3]);
        }
    }
}

// ---------------- K5: LayerNorm + @po_W + mel-mask ----------------
__global__ __launch_bounds__(384) void k5_out(const float* __restrict__ lng,
                                              const float* __restrict__ lnb,
                                              const float* __restrict__ poW,
                                              const float* __restrict__ ws,
                                              float* __restrict__ out){
    int b = blockIdx.y, t0 = blockIdx.x * 16;
    int mel = ((const int*)(ws + WS_ML))[b];
    __shared__ __align__(16) float upl[16*DDIM];
    __shared__ float mrow[16], rrow[16];
    for (int idx = threadIdx.x; idx < 16*DDIM; idx += 384){
        int r = idx / DDIM, cix = idx % DDIM;
        int t = t0 + r;
        upl[idx] = (t < TMM) ? ws[WS_UP + ((size_t)b*TMM + t)*DDIM + cix] : 0.f;
    }
    __syncthreads();
    if (threadIdx.x < 16){
        int r = threadIdx.x;
        float s = 0.f;
        for (int c = 0; c < DDIM; c++) s += upl[r*DDIM + c];
        float m = s * (1.f/DDIM);
        float v = 0.f;
        for (int c = 0; c < DDIM; c++){ float a = upl[r*DDIM + c] - m; v += a*a; }
        v *= (1.f/DDIM);
        mrow[r] = m; rrow[r] = rsqrtf(v + 1e-5f);
    }
    __syncthreads();
    for (int idx = threadIdx.x; idx < 16*DDIM; idx += 384){
        int r = idx / DDIM, cix = idx % DDIM;
        upl[idx] = (upl[idx] - mrow[r]) * rrow[r] * lng[cix] + lnb[cix];
    }
    __syncthreads();
    int j = threadIdx.x;  // 0..383
    float acc[16] = {};
    for (int k = 0; k < DDIM; k += 4){
        float po0 = poW[(k+0)*384 + j];
        float po1 = poW[(k+1)*384 + j];
        float po2 = poW[(k+2)*384 + j];
        float po3 = poW[(k+3)*384 + j];
        #pragma unroll
        for (int r = 0; r < 16; r++){
            float4 u = *(float4*)&upl[r*DDIM + k];
            acc[r] += u.x*po0 + u.y*po1 + u.z*po2 + u.w*po3;
        }
    }
    #pragma unroll
    for (int r = 0; r < 16; r++){
        int t = t0 + r;
        if (t < TMM)
            out[OUT_OUT + ((size_t)b*TMM + t)*384 + j] = (t < mel) ? acc[r] : 0.f;
    }
}

extern "C" void kernel_launch(void* const* d_in, const int* in_sizes, int n_in,
                              void* d_out, int out_size, void* d_ws, size_t ws_size,
                              hipStream_t stream){
    const float* duration  = (const float*)d_in[0];
    const float* tokens    = (const float*)d_in[1];
    const int*   src_len   = (const int*)d_in[2];
    // d_in[3] src_mask, d_in[4] tgt_len, d_in[5] max_src_len: recomputed/unused
    const float* cw_kernel = (const float*)d_in[6];
    const float* cw_bias   = (const float*)d_in[7];
    const float* cw_bng    = (const float*)d_in[8];
    const float* cw_bnb    = (const float*)d_in[9];
    const float* cw_bnm    = (const float*)d_in[10];
    const float* cw_bnv    = (const float*)d_in[11];
    const float* cw_lng    = (const float*)d_in[12];
    const float* cw_lnb    = (const float*)d_in[13];
    const float* sw_W1     = (const float*)d_in[14];
    const float* sw_b1     = (const float*)d_in[15];
    const float* sw_W2     = (const float*)d_in[16];
    const float* sw_b2     = (const float*)d_in[17];
    const float* sw_W3     = (const float*)d_in[18];
    const float* sw_b3     = (const float*)d_in[19];
    const float* lw_W      = (const float*)d_in[20];
    const float* lw_b      = (const float*)d_in[21];
    const float* cc_kernel = (const float*)d_in[22];
    const float* cc_bias   = (const float*)d_in[23];
    const float* cc_bng    = (const float*)d_in[24];
    const float* cc_bnb    = (const float*)d_in[25];
    const float* cc_bnm    = (const float*)d_in[26];
    const float* cc_bnv    = (const float*)d_in[27];
    const float* cc_lng    = (const float*)d_in[28];
    const float* cc_lnb    = (const float*)d_in[29];
    const float* sc_W1     = (const float*)d_in[30];
    const float* sc_b1     = (const float*)d_in[31];
    const float* sc_W2     = (const float*)d_in[32];
    const float* sc_b2     = (const float*)d_in[33];
    const float* sc_W3     = (const float*)d_in[34];
    const float* sc_b3     = (const float*)d_in[35];
    const float* le_W      = (const float*)d_in[36];
    const float* ln_gamma  = (const float*)d_in[37];
    const float* ln_beta   = (const float*)d_in[38];
    const float* po_W      = (const float*)d_in[39];
    float* out = (float*)d_out;
    float* ws  = (float*)d_ws;

    k0_scan<<<NB, TSZ, 0, stream>>>(duration, ws, out);
    k1_conv<<<dim3(16, NB), 256, 0, stream>>>(tokens,
        cw_kernel, cw_bias, cw_bng, cw_bnb, cw_bnm, cw_bnv, cw_lng, cw_lnb,
        cc_kernel, cc_bias, cc_bng, cc_bnb, cc_bnm, cc_bnv, cc_lng, cc_lnb,
        sw_W1, sw_b1, sc_W1, sc_b1, ws);
    k2_swish<<<dim3(250, NB), 256, 0, stream>>>(src_len,
        sw_W1, sw_W2, sw_b2, sw_W3, sw_b3,
        sc_W1, sc_W2, sc_b2, sc_W3, sc_b3, ws, out);
    k3_gemm1<<<dim3(16, 3, NB*4), 256, 0, stream>>>(out, tokens, ws);
    k4_gemm2<<<dim3(16, 3, NB), 256, 0, stream>>>(lw_W, lw_b, le_W, ws);
    k5_out<<<dim3(63, NB), 384, 0, stream>>>(ln_gamma, ln_beta, po_W, ws, out);
}

// Round 3
// 530.474 us; speedup vs baseline: 1.4047x; 1.3215x over previous
//
#include <hip/hip_runtime.h>
#include <math.h>

constexpr int NB = 16, TSZ = 512, DDIM = 192, NCO = 8, TMM = 1000;

// workspace layout (float indices)
constexpr int WS_SK  = 0;
constexpr int WS_EK  = WS_SK  + NB*TSZ;
constexpr int WS_VW1 = WS_EK  + NB*TSZ;
constexpr int WS_VC1 = WS_VW1 + NB*TSZ*4;
constexpr int WS_BC  = WS_VC1 + NB*TSZ*2;
constexpr int WS_UP  = WS_BC  + NB*TMM*8;
constexpr int WS_MT  = WS_UP  + NB*TMM*DDIM;            // bf16 M^T: NB*4*DDIM*TSZ shorts
constexpr int WS_ML  = WS_MT  + (NB*4*DDIM*TSZ)/2;      // NB ints live here

// output layout (float indices), tuple concat: out, ~mel_mask, mel_len, Wp, C
constexpr int OUT_OUT  = 0;
constexpr int OUT_MASK = NB*TMM*2*DDIM;            // 6,144,000
constexpr int OUT_MEL  = OUT_MASK + NB*TMM;        // 6,160,000
constexpr int OUT_WP   = OUT_MEL + NB;             // 6,160,016
constexpr int OUT_C    = OUT_WP + NB*4*TMM*TSZ;    // 38,928,016

typedef short short8  __attribute__((ext_vector_type(8)));
typedef short short4b __attribute__((ext_vector_type(4)));
typedef float floatx4 __attribute__((ext_vector_type(4)));

__device__ __forceinline__ float siluf(float x){ return x / (1.f + expf(-x)); }
__device__ __forceinline__ float silu_fast(float x){
    return x * __builtin_amdgcn_rcpf(1.f + __expf(-x));
}
__device__ __forceinline__ short f2bf(float x){
    union { float f; unsigned u; } v; v.f = x;
    unsigned r = v.u + 0x7fff + ((v.u >> 16) & 1);   // RNE
    return (short)(r >> 16);
}

// ---------------- K0: cumsum, mel_len, masks ----------------
__global__ __launch_bounds__(TSZ) void k0_scan(const float* __restrict__ dur,
                                               float* __restrict__ ws,
                                               float* __restrict__ out){
    int b = blockIdx.x, tid = threadIdx.x;
    __shared__ float buf[TSZ];
    __shared__ int smel;
    float d = dur[b*TSZ + tid];
    buf[tid] = d;
    __syncthreads();
    for (int off = 1; off < TSZ; off <<= 1){
        float v = (tid >= off) ? buf[tid - off] : 0.f;
        __syncthreads();
        buf[tid] += v;
        __syncthreads();
    }
    float ek = buf[tid];
    ws[WS_EK + b*TSZ + tid] = ek;
    ws[WS_SK + b*TSZ + tid] = ek - d;
    if (tid == 0){
        float tot = buf[TSZ-1];
        int mel = (int)rintf(tot);
        if (mel > TMM) mel = TMM;
        smel = mel;
        ((int*)(ws + WS_ML))[b] = mel;
        out[OUT_MEL + b] = (float)mel;
    }
    __syncthreads();
    int mel = smel;
    for (int t = tid; t < TMM; t += TSZ)
        out[OUT_MASK + b*TMM + t] = (t < mel) ? 1.f : 0.f;
}

// ---------------- K1: conv blocks + W1 pre-fold ----------------
__global__ __launch_bounds__(256) void k1_conv(const float* __restrict__ tokens,
    const float* __restrict__ cwk, const float* __restrict__ cwb,
    const float* __restrict__ cwg, const float* __restrict__ cwbe,
    const float* __restrict__ cwm, const float* __restrict__ cwv,
    const float* __restrict__ cwlg, const float* __restrict__ cwlb,
    const float* __restrict__ cck, const float* __restrict__ ccb,
    const float* __restrict__ ccg, const float* __restrict__ ccbe,
    const float* __restrict__ ccm, const float* __restrict__ ccv,
    const float* __restrict__ cclg, const float* __restrict__ cclb,
    const float* __restrict__ swW1, const float* __restrict__ swb1,
    const float* __restrict__ scW1, const float* __restrict__ scb1,
    float* __restrict__ ws){
    int b = blockIdx.y, s0 = blockIdx.x * 32;
    __shared__ float xt[34*DDIM];
    for (int idx = threadIdx.x; idx < 34*DDIM; idx += 256){
        int r = idx / DDIM, i = idx % DDIM;
        int s = s0 + r - 1;
        xt[idx] = (s >= 0 && s < TSZ) ? tokens[(b*TSZ + s)*DDIM + i] : 0.f;
    }
    __syncthreads();
    int sl = threadIdx.x >> 3, c = threadIdx.x & 7;
    float yw = cwb[c], yc = ccb[c];
    for (int k = 0; k < 3; k++){
        const float* xr = &xt[(sl + k)*DDIM];
        for (int i = 0; i < DDIM; i++){
            float xv = xr[i];
            yw += xv * cwk[(k*DDIM + i)*NCO + c];
            yc += xv * cck[(k*DDIM + i)*NCO + c];
        }
    }
    yw = (yw - cwm[c]) * rsqrtf(cwv[c] + 1e-5f) * cwg[c] + cwbe[c];
    yc = (yc - ccm[c]) * rsqrtf(ccv[c] + 1e-5f) * ccg[c] + ccbe[c];
    yw = siluf(yw);
    yc = siluf(yc);
    __shared__ float vwb[32][NCO], vcb[32][NCO];
    vwb[sl][c] = yw; vcb[sl][c] = yc;
    __syncthreads();
    float mw = 0.f, mc = 0.f;
    for (int j = 0; j < NCO; j++){ mw += vwb[sl][j]; mc += vcb[sl][j]; }
    mw *= (1.f/NCO); mc *= (1.f/NCO);
    float vw_ = 0.f, vc_ = 0.f;
    for (int j = 0; j < NCO; j++){
        float a = vwb[sl][j] - mw; vw_ += a*a;
        float e = vcb[sl][j] - mc; vc_ += e*e;
    }
    vw_ *= (1.f/NCO); vc_ *= (1.f/NCO);
    float lnw = (yw - mw) * rsqrtf(vw_ + 1e-5f) * cwlg[c] + cwlb[c];
    float lnc = (yc - mc) * rsqrtf(vc_ + 1e-5f) * cclg[c] + cclb[c];
    __syncthreads();
    vwb[sl][c] = lnw; vcb[sl][c] = lnc;
    __syncthreads();
    if (threadIdx.x < 32*4){
        int sl2 = threadIdx.x >> 2, j = threadIdx.x & 3;
        float acc = swb1[j];
        for (int cc2 = 0; cc2 < NCO; cc2++) acc += vwb[sl2][cc2] * swW1[(2+cc2)*4 + j];
        ws[WS_VW1 + (b*TSZ + s0 + sl2)*4 + j] = acc;
    }
    if (threadIdx.x < 32*2){
        int sl2 = threadIdx.x >> 1, j = threadIdx.x & 1;
        float acc = scb1[j];
        for (int cc2 = 0; cc2 < NCO; cc2++) acc += vcb[sl2][cc2] * scW1[(2+cc2)*2 + j];
        ws[WS_VC1 + (b*TSZ + s0 + sl2)*2 + j] = acc;
    }
}

// ---------------- K2: one wave per (b,t); 8 s-values per lane ----------------
__global__ __launch_bounds__(256) void k2_swish(const int* __restrict__ src_len,
    const float* __restrict__ swW1, const float* __restrict__ swW2,
    const float* __restrict__ swb2, const float* __restrict__ swW3,
    const float* __restrict__ swb3,
    const float* __restrict__ scW1, const float* __restrict__ scW2,
    const float* __restrict__ scb2, const float* __restrict__ scW3,
    const float* __restrict__ scb3,
    float* __restrict__ ws, float* __restrict__ out){
    int wid = threadIdx.x >> 6, lane = threadIdx.x & 63;
    int t = blockIdx.x * 4 + wid;          // grid.x = 250 -> t in [0,1000)
    int b = blockIdx.y;
    int mel = ((const int*)(ws + WS_ML))[b];
    int slen = src_len[b];
    bool tmask = (t >= mel);
    float tv = (float)(t + 1);

    float wr[8][4];     // W-MLP outputs (later overwritten with exp())
    float cv[8][2];     // C-MLP outputs
    float mx[4] = {-1e30f, -1e30f, -1e30f, -1e30f};

    #pragma unroll
    for (int i = 0; i < 8; i++){
        int s = i*64 + lane;
        bool smask = (s >= slen);
        bool am = smask || tmask;
        float sk = ws[WS_SK + b*TSZ + s];
        float ek = ws[WS_EK + b*TSZ + s];
        float Sv = am ? 0.f : (tv - sk);
        float Ev = am ? 0.f : (ek - tv);
        float4 vw1 = *(const float4*)&ws[WS_VW1 + (b*TSZ + s)*4];
        float2 vc1 = *(const float2*)&ws[WS_VC1 + (b*TSZ + s)*2];
        const float* vw1p = (const float*)&vw1;
        const float* vc1p = (const float*)&vc1;

        float h1[4], h2[4];
        #pragma unroll
        for (int j = 0; j < 4; j++)
            h1[j] = silu_fast(Sv*swW1[j] + Ev*swW1[4+j] + vw1p[j]);
        #pragma unroll
        for (int j = 0; j < 4; j++){
            float a = swb2[j];
            #pragma unroll
            for (int u = 0; u < 4; u++) a += h1[u]*swW2[u*4 + j];
            h2[j] = silu_fast(a);
        }
        #pragma unroll
        for (int q = 0; q < 4; q++){
            float a = swb3[q];
            #pragma unroll
            for (int u = 0; u < 4; u++) a += h2[u]*swW3[u*4 + q];
            float v = smask ? -1e30f : a;
            wr[i][q] = v;
            mx[q] = fmaxf(mx[q], v);
        }

        float c1[2], c2[2];
        #pragma unroll
        for (int j = 0; j < 2; j++)
            c1[j] = silu_fast(Sv*scW1[j] + Ev*scW1[2+j] + vc1p[j]);
        #pragma unroll
        for (int j = 0; j < 2; j++){
            float a = scb2[j];
            #pragma unroll
            for (int u = 0; u < 2; u++) a += c1[u]*scW2[u*2 + j];
            c2[j] = silu_fast(a);
        }
        #pragma unroll
        for (int p = 0; p < 2; p++){
            float a = scb3[p];
            #pragma unroll
            for (int u = 0; u < 2; u++) a += c2[u]*scW3[u*2 + p];
            cv[i][p] = a;
        }
        *(float2*)&out[OUT_C + ((size_t)(b*TMM + t)*TSZ + s)*2] =
            make_float2(cv[i][0], cv[i][1]);
    }

    // wave butterfly: max per q
    #pragma unroll
    for (int q = 0; q < 4; q++)
        #pragma unroll
        for (int o = 32; o; o >>= 1)
            mx[q] = fmaxf(mx[q], __shfl_xor(mx[q], o, 64));

    // exp + local sum
    float sum[4] = {0.f, 0.f, 0.f, 0.f};
    #pragma unroll
    for (int i = 0; i < 8; i++)
        #pragma unroll
        for (int q = 0; q < 4; q++){
            float p = __expf(wr[i][q] - mx[q]);
            wr[i][q] = p;
            sum[q] += p;
        }
    #pragma unroll
    for (int q = 0; q < 4; q++)
        #pragma unroll
        for (int o = 32; o; o >>= 1)
            sum[q] += __shfl_xor(sum[q], o, 64);
    float rs[4];
    #pragma unroll
    for (int q = 0; q < 4; q++) rs[q] = __builtin_amdgcn_rcpf(sum[q]);

    // normalize, write Wp, accumulate Bc
    float bc[8] = {0.f,0.f,0.f,0.f,0.f,0.f,0.f,0.f};
    #pragma unroll
    for (int i = 0; i < 8; i++){
        int s = i*64 + lane;
        #pragma unroll
        for (int q = 0; q < 4; q++){
            float w = tmask ? 0.f : wr[i][q]*rs[q];
            out[OUT_WP + ((size_t)(b*4 + q)*TMM + t)*TSZ + s] = w;
            bc[q*2 + 0] += w*cv[i][0];
            bc[q*2 + 1] += w*cv[i][1];
        }
    }
    #pragma unroll
    for (int j = 0; j < 8; j++)
        #pragma unroll
        for (int o = 32; o; o >>= 1)
            bc[j] += __shfl_xor(bc[j], o, 64);
    if (lane == 0){
        *(float4*)&ws[WS_BC + (b*TMM + t)*8 + 0] = make_float4(bc[0], bc[1], bc[2], bc[3]);
        *(float4*)&ws[WS_BC + (b*TMM + t)*8 + 4] = make_float4(bc[4], bc[5], bc[6], bc[7]);
    }
}

// ---------------- K3: M^T[b][q][d][s] = (tokens @ lwW_q)^T in bf16, MFMA ----------------
__global__ __launch_bounds__(256) void k3_mgemm(const float* __restrict__ tokens,
                                                const float* __restrict__ lwW,
                                                float* __restrict__ ws){
    int b = blockIdx.z;
    int s0 = blockIdx.x * 64;
    int y = blockIdx.y;              // 0..11 -> (q, d-tile)
    int q = y / 3, d0 = (y % 3) * 64;
    __shared__ short A_sm[64*200];   // [d_local][h], pad to 200
    __shared__ short B_sm[64*200];   // [s_local][h]
    int tid = threadIdx.x;
    // stage A: A_sm[md][h] = bf16(lwW[(q*192+h)*192 + d0+md])  (transpose)
    for (int r = 0; r < 12; r++){
        int c = tid + r*256;
        int h = c >> 4, p = c & 15;
        float4 v = *(const float4*)&lwW[((size_t)(q*DDIM + h))*DDIM + d0 + p*4];
        A_sm[(p*4+0)*200 + h] = f2bf(v.x);
        A_sm[(p*4+1)*200 + h] = f2bf(v.y);
        A_sm[(p*4+2)*200 + h] = f2bf(v.z);
        A_sm[(p*4+3)*200 + h] = f2bf(v.w);
    }
    // stage B: B_sm[sl][h] = bf16(tokens[(b*512+s0+sl)*192 + h])
    {
        int row = tid >> 2, part = tid & 3;
        const float* src = &tokens[((size_t)b*TSZ + s0 + row)*DDIM];
        #pragma unroll
        for (int j = 0; j < 12; j++){
            int f = part + j*4;
            float4 v = *(const float4*)&src[f*4];
            short4b wv; wv.x=f2bf(v.x); wv.y=f2bf(v.y); wv.z=f2bf(v.z); wv.w=f2bf(v.w);
            *(short4b*)&B_sm[row*200 + f*4] = wv;
        }
    }
    __syncthreads();
    int w = tid >> 6, lane = tid & 63;
    int wm = (w & 1)*32, wn = (w >> 1)*32;
    int ln = lane & 15, qd = lane >> 4;
    floatx4 acc[2][2] = {};
    for (int k0 = 0; k0 < DDIM; k0 += 32){
        short8 a0 = *(short8*)&A_sm[(wm + ln)*200 + k0 + qd*8];
        short8 a1 = *(short8*)&A_sm[(wm + 16 + ln)*200 + k0 + qd*8];
        short8 b0 = *(short8*)&B_sm[(wn + ln)*200 + k0 + qd*8];
        short8 b1 = *(short8*)&B_sm[(wn + 16 + ln)*200 + k0 + qd*8];
        acc[0][0] = __builtin_amdgcn_mfma_f32_16x16x32_bf16(a0, b0, acc[0][0], 0,0,0);
        acc[0][1] = __builtin_amdgcn_mfma_f32_16x16x32_bf16(a0, b1, acc[0][1], 0,0,0);
        acc[1][0] = __builtin_amdgcn_mfma_f32_16x16x32_bf16(a1, b0, acc[1][0], 0,0,0);
        acc[1][1] = __builtin_amdgcn_mfma_f32_16x16x32_bf16(a1, b1, acc[1][1], 0,0,0);
    }
    short* mt = (short*)(ws + WS_MT);
    #pragma unroll
    for (int mi = 0; mi < 2; mi++)
      #pragma unroll
      for (int ni = 0; ni < 2; ni++)
        #pragma unroll
        for (int r = 0; r < 4; r++){
            int d = d0 + wm + mi*16 + qd*4 + r;
            int s = s0 + wn + ni*16 + ln;
            mt[((size_t)(b*4 + q)*DDIM + d)*TSZ + s] = f2bf(acc[mi][ni][r]);
        }
}

// ---------------- K4: up = Wp(bf16) @ M(bf16) over K=2048 + lw_b + Bc@le_W ----------------
__global__ __launch_bounds__(256) void k4_upgemm(const float* __restrict__ outbuf,
                                                 const float* __restrict__ lwb,
                                                 const float* __restrict__ leW,
                                                 float* __restrict__ ws){
    int b = blockIdx.z;
    int t0 = blockIdx.x * 64;
    int d0 = blockIdx.y * 64;
    __shared__ short A_sm[64*72];    // [t_local][k], pad 72
    __shared__ short B_sm[64*72];    // [d_local][k]
    const short* mt = (const short*)(ws + WS_MT);
    int tid = threadIdx.x;
    int w = tid >> 6, lane = tid & 63;
    int wm = (w & 1)*32, wn = (w >> 1)*32;
    int ln = lane & 15, qd = lane >> 4;
    floatx4 acc[2][2] = {};
    int tlA = tid >> 2, partA = tid & 3;
    for (int kc = 0; kc < 32; kc++){
        int q = kc >> 3, ss0 = (kc & 7)*64;
        // stage A: Wp fp32 -> bf16
        {
            int t = t0 + tlA;
            if (t < TMM){
                const float* src = &outbuf[OUT_WP + ((size_t)(b*4+q)*TMM + t)*TSZ + ss0];
                #pragma unroll
                for (int j = 0; j < 4; j++){
                    int f = partA + j*4;
                    float4 v = *(const float4*)&src[f*4];
                    short4b wv; wv.x=f2bf(v.x); wv.y=f2bf(v.y); wv.z=f2bf(v.z); wv.w=f2bf(v.w);
                    *(short4b*)&A_sm[tlA*72 + f*4] = wv;
                }
            } else {
                #pragma unroll
                for (int j = 0; j < 4; j++){
                    int f = partA + j*4;
                    short4b z = {0,0,0,0};
                    *(short4b*)&A_sm[tlA*72 + f*4] = z;
                }
            }
        }
        // stage B from mt (already bf16, [d][s] layout)
        #pragma unroll
        for (int r = 0; r < 2; r++){
            int c = tid + r*256;
            int row = c >> 3, off = c & 7;
            short8 v = *(const short8*)&mt[((size_t)(b*4+q)*DDIM + d0 + row)*TSZ + ss0 + off*8];
            *(short8*)&B_sm[row*72 + off*8] = v;
        }
        __syncthreads();
        #pragma unroll
        for (int k0 = 0; k0 < 64; k0 += 32){
            short8 a0 = *(short8*)&A_sm[(wm + ln)*72 + k0 + qd*8];
            short8 a1 = *(short8*)&A_sm[(wm + 16 + ln)*72 + k0 + qd*8];
            short8 b0 = *(short8*)&B_sm[(wn + ln)*72 + k0 + qd*8];
            short8 b1 = *(short8*)&B_sm[(wn + 16 + ln)*72 + k0 + qd*8];
            acc[0][0] = __builtin_amdgcn_mfma_f32_16x16x32_bf16(a0, b0, acc[0][0], 0,0,0);
            acc[0][1] = __builtin_amdgcn_mfma_f32_16x16x32_bf16(a0, b1, acc[0][1], 0,0,0);
            acc[1][0] = __builtin_amdgcn_mfma_f32_16x16x32_bf16(a1, b0, acc[1][0], 0,0,0);
            acc[1][1] = __builtin_amdgcn_mfma_f32_16x16x32_bf16(a1, b1, acc[1][1], 0,0,0);
        }
        __syncthreads();
    }
    // epilogue: + lw_b + Bc @ le_W
    float le[2][8], lwbv[2];
    #pragma unroll
    for (int ni = 0; ni < 2; ni++){
        int d = d0 + wn + ni*16 + ln;
        lwbv[ni] = lwb[d];
        #pragma unroll
        for (int j = 0; j < 8; j++) le[ni][j] = leW[j*DDIM + d];
    }
    #pragma unroll
    for (int mi = 0; mi < 2; mi++){
        #pragma unroll
        for (int r = 0; r < 4; r++){
            int t = t0 + wm + mi*16 + qd*4 + r;
            if (t < TMM){
                float4 b0 = *(const float4*)&ws[WS_BC + (b*TMM + t)*8];
                float4 b1 = *(const float4*)&ws[WS_BC + (b*TMM + t)*8 + 4];
                float bcv[8] = {b0.x,b0.y,b0.z,b0.w,b1.x,b1.y,b1.z,b1.w};
                #pragma unroll
                for (int ni = 0; ni < 2; ni++){
                    int d = d0 + wn + ni*16 + ln;
                    float a = acc[mi][ni][r] + lwbv[ni];
                    #pragma unroll
                    for (int j = 0; j < 8; j++) a += bcv[j]*le[ni][j];
                    ws[WS_UP + ((size_t)b*TMM + t)*DDIM + d] = a;
                }
            }
        }
    }
}

// ---------------- K5: LayerNorm + @po_W + mel-mask ----------------
__global__ __launch_bounds__(384) void k5_out(const float* __restrict__ lng,
                                              const float* __restrict__ lnb,
                                              const float* __restrict__ poW,
                                              const float* __restrict__ ws,
                                              float* __restrict__ out){
    int b = blockIdx.y, t0 = blockIdx.x * 16;
    int mel = ((const int*)(ws + WS_ML))[b];
    __shared__ __align__(16) float upl[16*DDIM];
    __shared__ float mrow[16], rrow[16];
    for (int idx = threadIdx.x; idx < 16*DDIM; idx += 384){
        int r = idx / DDIM, cix = idx % DDIM;
        int t = t0 + r;
        upl[idx] = (t < TMM) ? ws[WS_UP + ((size_t)b*TMM + t)*DDIM + cix] : 0.f;
    }
    __syncthreads();
    if (threadIdx.x < 16){
        int r = threadIdx.x;
        float s = 0.f;
        for (int c = 0; c < DDIM; c++) s += upl[r*DDIM + c];
        float m = s * (1.f/DDIM);
        float v = 0.f;
        for (int c = 0; c < DDIM; c++){ float a = upl[r*DDIM + c] - m; v += a*a; }
        v *= (1.f/DDIM);
        mrow[r] = m; rrow[r] = rsqrtf(v + 1e-5f);
    }
    __syncthreads();
    for (int idx = threadIdx.x; idx < 16*DDIM; idx += 384){
        int r = idx / DDIM, cix = idx % DDIM;
        upl[idx] = (upl[idx] - mrow[r]) * rrow[r] * lng[cix] + lnb[cix];
    }
    __syncthreads();
    int j = threadIdx.x;  // 0..383
    float acc[16] = {};
    for (int k = 0; k < DDIM; k += 4){
        float po0 = poW[(k+0)*384 + j];
        float po1 = poW[(k+1)*384 + j];
        float po2 = poW[(k+2)*384 + j];
        float po3 = poW[(k+3)*384 + j];
        #pragma unroll
        for (int r = 0; r < 16; r++){
            float4 u = *(float4*)&upl[r*DDIM + k];
            acc[r] += u.x*po0 + u.y*po1 + u.z*po2 + u.w*po3;
        }
    }
    #pragma unroll
    for (int r = 0; r < 16; r++){
        int t = t0 + r;
        if (t < TMM)
            out[OUT_OUT + ((size_t)b*TMM + t)*384 + j] = (t < mel) ? acc[r] : 0.f;
    }
}

extern "C" void kernel_launch(void* const* d_in, const int* in_sizes, int n_in,
                              void* d_out, int out_size, void* d_ws, size_t ws_size,
                              hipStream_t stream){
    const float* duration  = (const float*)d_in[0];
    const float* tokens    = (const float*)d_in[1];
    const int*   src_len   = (const int*)d_in[2];
    const float* cw_kernel = (const float*)d_in[6];
    const float* cw_bias   = (const float*)d_in[7];
    const float* cw_bng    = (const float*)d_in[8];
    const float* cw_bnb    = (const float*)d_in[9];
    const float* cw_bnm    = (const float*)d_in[10];
    const float* cw_bnv    = (const float*)d_in[11];
    const float* cw_lng    = (const float*)d_in[12];
    const float* cw_lnb    = (const float*)d_in[13];
    const float* sw_W1     = (const float*)d_in[14];
    const float* sw_b1     = (const float*)d_in[15];
    const float* sw_W2     = (const float*)d_in[16];
    const float* sw_b2     = (const float*)d_in[17];
    const float* sw_W3     = (const float*)d_in[18];
    const float* sw_b3     = (const float*)d_in[19];
    const float* lw_W      = (const float*)d_in[20];
    const float* lw_b      = (const float*)d_in[21];
    const float* cc_kernel = (const float*)d_in[22];
    const float* cc_bias   = (const float*)d_in[23];
    const float* cc_bng    = (const float*)d_in[24];
    const float* cc_bnb    = (const float*)d_in[25];
    const float* cc_bnm    = (const float*)d_in[26];
    const float* cc_bnv    = (const float*)d_in[27];
    const float* cc_lng    = (const float*)d_in[28];
    const float* cc_lnb    = (const float*)d_in[29];
    const float* sc_W1     = (const float*)d_in[30];
    const float* sc_b1     = (const float*)d_in[31];
    const float* sc_W2     = (const float*)d_in[32];
    const float* sc_b2     = (const float*)d_in[33];
    const float* sc_W3     = (const float*)d_in[34];
    const float* sc_b3     = (const float*)d_in[35];
    const float* le_W      = (const float*)d_in[36];
    const float* ln_gamma  = (const float*)d_in[37];
    const float* ln_beta   = (const float*)d_in[38];
    const float* po_W      = (const float*)d_in[39];
    float* out = (float*)d_out;
    float* ws  = (float*)d_ws;

    k0_scan<<<NB, TSZ, 0, stream>>>(duration, ws, out);
    k1_conv<<<dim3(16, NB), 256, 0, stream>>>(tokens,
        cw_kernel, cw_bias, cw_bng, cw_bnb, cw_bnm, cw_bnv, cw_lng, cw_lnb,
        cc_kernel, cc_bias, cc_bng, cc_bnb, cc_bnm, cc_bnv, cc_lng, cc_lnb,
        sw_W1, sw_b1, sc_W1, sc_b1, ws);
    k2_swish<<<dim3(250, NB), 256, 0, stream>>>(src_len,
        sw_W1, sw_W2, sw_b2, sw_W3, sw_b3,
        sc_W1, sc_W2, sc_b2, sc_W3, sc_b3, ws, out);
    k3_mgemm<<<dim3(8, 12, NB), 256, 0, stream>>>(tokens, lw_W, ws);
    k4_upgemm<<<dim3(16, 3, NB), 256, 0, stream>>>(out, lw_b, le_W, ws);
    k5_out<<<dim3(63, NB), 384, 0, stream>>>(ln_gamma, ln_beta, po_W, ws, out);
}

// Round 4
// 472.820 us; speedup vs baseline: 1.5760x; 1.1219x over previous
//
#include <hip/hip_runtime.h>
#include <math.h>

constexpr int NB = 16, TSZ = 512, DDIM = 192, NCO = 8, TMM = 1000;

// workspace layout (float indices)
constexpr int WS_SK  = 0;
constexpr int WS_EK  = WS_SK  + NB*TSZ;
constexpr int WS_VW1 = WS_EK  + NB*TSZ;
constexpr int WS_VC1 = WS_VW1 + NB*TSZ*4;
constexpr int WS_BC  = WS_VC1 + NB*TSZ*2;
constexpr int WS_UP  = WS_BC  + NB*TMM*8;
constexpr int WS_MT  = WS_UP  + NB*TMM*DDIM;            // bf16 M^T: NB*4*DDIM*TSZ shorts
constexpr int WS_ML  = WS_MT  + (NB*4*DDIM*TSZ)/2;      // NB ints live here

// output layout (float indices), tuple concat: out, ~mel_mask, mel_len, Wp, C
constexpr int OUT_OUT  = 0;
constexpr int OUT_MASK = NB*TMM*2*DDIM;            // 6,144,000
constexpr int OUT_MEL  = OUT_MASK + NB*TMM;        // 6,160,000
constexpr int OUT_WP   = OUT_MEL + NB;             // 6,160,016
constexpr int OUT_C    = OUT_WP + NB*4*TMM*TSZ;    // 38,928,016

typedef short short8  __attribute__((ext_vector_type(8)));
typedef short short4b __attribute__((ext_vector_type(4)));
typedef float floatx4 __attribute__((ext_vector_type(4)));

__device__ __forceinline__ float siluf(float x){ return x / (1.f + expf(-x)); }
__device__ __forceinline__ float silu_fast(float x){
    return x * __builtin_amdgcn_rcpf(1.f + __expf(-x));
}
__device__ __forceinline__ short f2bf(float x){
    union { float f; unsigned u; } v; v.f = x;
    unsigned r = v.u + 0x7fff + ((v.u >> 16) & 1);   // RNE
    return (short)(r >> 16);
}

// ---------------- K0: cumsum, mel_len, masks ----------------
__global__ __launch_bounds__(TSZ) void k0_scan(const float* __restrict__ dur,
                                               float* __restrict__ ws,
                                               float* __restrict__ out){
    int b = blockIdx.x, tid = threadIdx.x;
    __shared__ float buf[TSZ];
    __shared__ int smel;
    float d = dur[b*TSZ + tid];
    buf[tid] = d;
    __syncthreads();
    for (int off = 1; off < TSZ; off <<= 1){
        float v = (tid >= off) ? buf[tid - off] : 0.f;
        __syncthreads();
        buf[tid] += v;
        __syncthreads();
    }
    float ek = buf[tid];
    ws[WS_EK + b*TSZ + tid] = ek;
    ws[WS_SK + b*TSZ + tid] = ek - d;
    if (tid == 0){
        float tot = buf[TSZ-1];
        int mel = (int)rintf(tot);
        if (mel > TMM) mel = TMM;
        smel = mel;
        ((int*)(ws + WS_ML))[b] = mel;
        out[OUT_MEL + b] = (float)mel;
    }
    __syncthreads();
    int mel = smel;
    for (int t = tid; t < TMM; t += TSZ)
        out[OUT_MASK + b*TMM + t] = (t < mel) ? 1.f : 0.f;
}

// ---------------- K1: conv blocks + W1 pre-fold (512 thr, split-K x2) ----------------
__global__ __launch_bounds__(512) void k1_conv(const float* __restrict__ tokens,
    const float* __restrict__ cwk, const float* __restrict__ cwb,
    const float* __restrict__ cwg, const float* __restrict__ cwbe,
    const float* __restrict__ cwm, const float* __restrict__ cwv,
    const float* __restrict__ cwlg, const float* __restrict__ cwlb,
    const float* __restrict__ cck, const float* __restrict__ ccb,
    const float* __restrict__ ccg, const float* __restrict__ ccbe,
    const float* __restrict__ ccm, const float* __restrict__ ccv,
    const float* __restrict__ cclg, const float* __restrict__ cclb,
    const float* __restrict__ swW1, const float* __restrict__ swb1,
    const float* __restrict__ scW1, const float* __restrict__ scb1,
    float* __restrict__ ws){
    int b = blockIdx.y, s0 = blockIdx.x * 32;
    __shared__ float xt[34*DDIM];
    for (int idx = threadIdx.x; idx < 34*DDIM; idx += 512){
        int r = idx / DDIM, i = idx % DDIM;
        int s = s0 + r - 1;
        xt[idx] = (s >= 0 && s < TSZ) ? tokens[(b*TSZ + s)*DDIM + i] : 0.f;
    }
    __syncthreads();
    int tid = threadIdx.x;
    int tid2 = tid >> 1, h = tid & 1;
    int sl = tid2 >> 3, c = tid2 & 7;
    int i0 = h * 96;
    float yw = h ? 0.f : cwb[c];
    float yc = h ? 0.f : ccb[c];
    for (int k = 0; k < 3; k++){
        const float* xr = &xt[(sl + k)*DDIM + i0];
        const float* kw = &cwk[((size_t)(k*DDIM + i0))*NCO + c];
        const float* kc = &cck[((size_t)(k*DDIM + i0))*NCO + c];
        for (int i = 0; i < 96; i++){
            float xv = xr[i];
            yw += xv * kw[i*NCO];
            yc += xv * kc[i*NCO];
        }
    }
    yw += __shfl_xor(yw, 1, 64);
    yc += __shfl_xor(yc, 1, 64);
    yw = (yw - cwm[c]) * rsqrtf(cwv[c] + 1e-5f) * cwg[c] + cwbe[c];
    yc = (yc - ccm[c]) * rsqrtf(ccv[c] + 1e-5f) * ccg[c] + ccbe[c];
    yw = siluf(yw);
    yc = siluf(yc);
    __shared__ float vwb[32][NCO], vcb[32][NCO];
    if (h == 0){ vwb[sl][c] = yw; vcb[sl][c] = yc; }
    __syncthreads();
    float mw = 0.f, mc = 0.f;
    for (int j = 0; j < NCO; j++){ mw += vwb[sl][j]; mc += vcb[sl][j]; }
    mw *= (1.f/NCO); mc *= (1.f/NCO);
    float vw_ = 0.f, vc_ = 0.f;
    for (int j = 0; j < NCO; j++){
        float a = vwb[sl][j] - mw; vw_ += a*a;
        float e = vcb[sl][j] - mc; vc_ += e*e;
    }
    vw_ *= (1.f/NCO); vc_ *= (1.f/NCO);
    float lnw = (yw - mw) * rsqrtf(vw_ + 1e-5f) * cwlg[c] + cwlb[c];
    float lnc = (yc - mc) * rsqrtf(vc_ + 1e-5f) * cclg[c] + cclb[c];
    __syncthreads();
    if (h == 0){ vwb[sl][c] = lnw; vcb[sl][c] = lnc; }
    __syncthreads();
    if (tid < 32*4){
        int sl2 = tid >> 2, j = tid & 3;
        float acc = swb1[j];
        for (int cc2 = 0; cc2 < NCO; cc2++) acc += vwb[sl2][cc2] * swW1[(2+cc2)*4 + j];
        ws[WS_VW1 + (b*TSZ + s0 + sl2)*4 + j] = acc;
    }
    if (tid < 32*2){
        int sl2 = tid >> 1, j = tid & 1;
        float acc = scb1[j];
        for (int cc2 = 0; cc2 < NCO; cc2++) acc += vcb[sl2][cc2] * scW1[(2+cc2)*2 + j];
        ws[WS_VC1 + (b*TSZ + s0 + sl2)*2 + j] = acc;
    }
}

// ---------------- K2: one wave per (b,t); 8 s-values per lane ----------------
__global__ __launch_bounds__(256) void k2_swish(const int* __restrict__ src_len,
    const float* __restrict__ swW1, const float* __restrict__ swW2,
    const float* __restrict__ swb2, const float* __restrict__ swW3,
    const float* __restrict__ swb3,
    const float* __restrict__ scW1, const float* __restrict__ scW2,
    const float* __restrict__ scb2, const float* __restrict__ scW3,
    const float* __restrict__ scb3,
    float* __restrict__ ws, float* __restrict__ out){
    int wid = threadIdx.x >> 6, lane = threadIdx.x & 63;
    int t = blockIdx.x * 4 + wid;          // grid.x = 250 -> t in [0,1000)
    int b = blockIdx.y;
    int mel = ((const int*)(ws + WS_ML))[b];
    int slen = src_len[b];
    bool tmask = (t >= mel);
    float tv = (float)(t + 1);

    float wr[8][4];     // W-MLP outputs (later overwritten with exp())
    float cv[8][2];     // C-MLP outputs
    float mx[4] = {-1e30f, -1e30f, -1e30f, -1e30f};

    #pragma unroll
    for (int i = 0; i < 8; i++){
        int s = i*64 + lane;
        bool smask = (s >= slen);
        bool am = smask || tmask;
        float sk = ws[WS_SK + b*TSZ + s];
        float ek = ws[WS_EK + b*TSZ + s];
        float Sv = am ? 0.f : (tv - sk);
        float Ev = am ? 0.f : (ek - tv);
        float4 vw1 = *(const float4*)&ws[WS_VW1 + (b*TSZ + s)*4];
        float2 vc1 = *(const float2*)&ws[WS_VC1 + (b*TSZ + s)*2];
        const float* vw1p = (const float*)&vw1;
        const float* vc1p = (const float*)&vc1;

        float h1[4], h2[4];
        #pragma unroll
        for (int j = 0; j < 4; j++)
            h1[j] = silu_fast(Sv*swW1[j] + Ev*swW1[4+j] + vw1p[j]);
        #pragma unroll
        for (int j = 0; j < 4; j++){
            float a = swb2[j];
            #pragma unroll
            for (int u = 0; u < 4; u++) a += h1[u]*swW2[u*4 + j];
            h2[j] = silu_fast(a);
        }
        #pragma unroll
        for (int q = 0; q < 4; q++){
            float a = swb3[q];
            #pragma unroll
            for (int u = 0; u < 4; u++) a += h2[u]*swW3[u*4 + q];
            float v = smask ? -1e30f : a;
            wr[i][q] = v;
            mx[q] = fmaxf(mx[q], v);
        }

        float c1[2], c2[2];
        #pragma unroll
        for (int j = 0; j < 2; j++)
            c1[j] = silu_fast(Sv*scW1[j] + Ev*scW1[2+j] + vc1p[j]);
        #pragma unroll
        for (int j = 0; j < 2; j++){
            float a = scb2[j];
            #pragma unroll
            for (int u = 0; u < 2; u++) a += c1[u]*scW2[u*2 + j];
            c2[j] = silu_fast(a);
        }
        #pragma unroll
        for (int p = 0; p < 2; p++){
            float a = scb3[p];
            #pragma unroll
            for (int u = 0; u < 2; u++) a += c2[u]*scW3[u*2 + p];
            cv[i][p] = a;
        }
        *(float2*)&out[OUT_C + ((size_t)(b*TMM + t)*TSZ + s)*2] =
            make_float2(cv[i][0], cv[i][1]);
    }

    // wave butterfly: max per q
    #pragma unroll
    for (int q = 0; q < 4; q++)
        #pragma unroll
        for (int o = 32; o; o >>= 1)
            mx[q] = fmaxf(mx[q], __shfl_xor(mx[q], o, 64));

    // exp + local sum
    float sum[4] = {0.f, 0.f, 0.f, 0.f};
    #pragma unroll
    for (int i = 0; i < 8; i++)
        #pragma unroll
        for (int q = 0; q < 4; q++){
            float p = __expf(wr[i][q] - mx[q]);
            wr[i][q] = p;
            sum[q] += p;
        }
    #pragma unroll
    for (int q = 0; q < 4; q++)
        #pragma unroll
        for (int o = 32; o; o >>= 1)
            sum[q] += __shfl_xor(sum[q], o, 64);
    float rs[4];
    #pragma unroll
    for (int q = 0; q < 4; q++) rs[q] = __builtin_amdgcn_rcpf(sum[q]);

    // normalize, write Wp, accumulate Bc
    float bc[8] = {0.f,0.f,0.f,0.f,0.f,0.f,0.f,0.f};
    #pragma unroll
    for (int i = 0; i < 8; i++){
        int s = i*64 + lane;
        #pragma unroll
        for (int q = 0; q < 4; q++){
            float w = tmask ? 0.f : wr[i][q]*rs[q];
            out[OUT_WP + ((size_t)(b*4 + q)*TMM + t)*TSZ + s] = w;
            bc[q*2 + 0] += w*cv[i][0];
            bc[q*2 + 1] += w*cv[i][1];
        }
    }
    #pragma unroll
    for (int j = 0; j < 8; j++)
        #pragma unroll
        for (int o = 32; o; o >>= 1)
            bc[j] += __shfl_xor(bc[j], o, 64);
    if (lane == 0){
        *(float4*)&ws[WS_BC + (b*TMM + t)*8 + 0] = make_float4(bc[0], bc[1], bc[2], bc[3]);
        *(float4*)&ws[WS_BC + (b*TMM + t)*8 + 4] = make_float4(bc[4], bc[5], bc[6], bc[7]);
    }
}

// ---------------- K3: M^T[b][q][d][s] = (tokens @ lwW_q)^T in bf16, MFMA ----------------
__global__ __launch_bounds__(256) void k3_mgemm(const float* __restrict__ tokens,
                                                const float* __restrict__ lwW,
                                                float* __restrict__ ws){
    int b = blockIdx.z;
    int s0 = blockIdx.x * 64;
    int y = blockIdx.y;              // 0..11 -> (q, d-tile)
    int q = y / 3, d0 = (y % 3) * 64;
    __shared__ short A_sm[64*200];   // [d_local][h], pad to 200
    __shared__ short B_sm[64*200];   // [s_local][h]
    int tid = threadIdx.x;
    // stage A: A_sm[md][h] = bf16(lwW[(q*192+h)*192 + d0+md])  (transpose)
    for (int r = 0; r < 12; r++){
        int c = tid + r*256;
        int h = c >> 4, p = c & 15;
        float4 v = *(const float4*)&lwW[((size_t)(q*DDIM + h))*DDIM + d0 + p*4];
        A_sm[(p*4+0)*200 + h] = f2bf(v.x);
        A_sm[(p*4+1)*200 + h] = f2bf(v.y);
        A_sm[(p*4+2)*200 + h] = f2bf(v.z);
        A_sm[(p*4+3)*200 + h] = f2bf(v.w);
    }
    // stage B: B_sm[sl][h] = bf16(tokens[(b*512+s0+sl)*192 + h])
    {
        int row = tid >> 2, part = tid & 3;
        const float* src = &tokens[((size_t)b*TSZ + s0 + row)*DDIM];
        #pragma unroll
        for (int j = 0; j < 12; j++){
            int f = part + j*4;
            float4 v = *(const float4*)&src[f*4];
            short4b wv; wv.x=f2bf(v.x); wv.y=f2bf(v.y); wv.z=f2bf(v.z); wv.w=f2bf(v.w);
            *(short4b*)&B_sm[row*200 + f*4] = wv;
        }
    }
    __syncthreads();
    int w = tid >> 6, lane = tid & 63;
    int wm = (w & 1)*32, wn = (w >> 1)*32;
    int ln = lane & 15, qd = lane >> 4;
    floatx4 acc[2][2] = {};
    for (int k0 = 0; k0 < DDIM; k0 += 32){
        short8 a0 = *(short8*)&A_sm[(wm + ln)*200 + k0 + qd*8];
        short8 a1 = *(short8*)&A_sm[(wm + 16 + ln)*200 + k0 + qd*8];
        short8 b0 = *(short8*)&B_sm[(wn + ln)*200 + k0 + qd*8];
        short8 b1 = *(short8*)&B_sm[(wn + 16 + ln)*200 + k0 + qd*8];
        acc[0][0] = __builtin_amdgcn_mfma_f32_16x16x32_bf16(a0, b0, acc[0][0], 0,0,0);
        acc[0][1] = __builtin_amdgcn_mfma_f32_16x16x32_bf16(a0, b1, acc[0][1], 0,0,0);
        acc[1][0] = __builtin_amdgcn_mfma_f32_16x16x32_bf16(a1, b0, acc[1][0], 0,0,0);
        acc[1][1] = __builtin_amdgcn_mfma_f32_16x16x32_bf16(a1, b1, acc[1][1], 0,0,0);
    }
    short* mt = (short*)(ws + WS_MT);
    #pragma unroll
    for (int mi = 0; mi < 2; mi++)
      #pragma unroll
      for (int ni = 0; ni < 2; ni++)
        #pragma unroll
        for (int r = 0; r < 4; r++){
            int d = d0 + wm + mi*16 + qd*4 + r;
            int s = s0 + wn + ni*16 + ln;
            mt[((size_t)(b*4 + q)*DDIM + d)*TSZ + s] = f2bf(acc[mi][ni][r]);
        }
}

// ---------------- K4: up = Wp(bf16) @ M(bf16) over K=2048 + lw_b + Bc@le_W ----------------
__global__ __launch_bounds__(256) void k4_upgemm(const float* __restrict__ outbuf,
                                                 const float* __restrict__ lwb,
                                                 const float* __restrict__ leW,
                                                 float* __restrict__ ws){
    int b = blockIdx.z;
    int t0 = blockIdx.x * 64;
    int d0 = blockIdx.y * 64;
    __shared__ short A_sm[64*72];    // [t_local][k], pad 72
    __shared__ short B_sm[64*72];    // [d_local][k]
    const short* mt = (const short*)(ws + WS_MT);
    int tid = threadIdx.x;
    int w = tid >> 6, lane = tid & 63;
    int wm = (w & 1)*32, wn = (w >> 1)*32;
    int ln = lane & 15, qd = lane >> 4;
    floatx4 acc[2][2] = {};
    int tlA = tid >> 2, partA = tid & 3;
    for (int kc = 0; kc < 32; kc++){
        int q = kc >> 3, ss0 = (kc & 7)*64;
        // stage A: Wp fp32 -> bf16
        {
            int t = t0 + tlA;
            if (t < TMM){
                const float* src = &outbuf[OUT_WP + ((size_t)(b*4+q)*TMM + t)*TSZ + ss0];
                #pragma unroll
                for (int j = 0; j < 4; j++){
                    int f = partA + j*4;
                    float4 v = *(const float4*)&src[f*4];
                    short4b wv; wv.x=f2bf(v.x); wv.y=f2bf(v.y); wv.z=f2bf(v.z); wv.w=f2bf(v.w);
                    *(short4b*)&A_sm[tlA*72 + f*4] = wv;
                }
            } else {
                #pragma unroll
                for (int j = 0; j < 4; j++){
                    int f = partA + j*4;
                    short4b z = {0,0,0,0};
                    *(short4b*)&A_sm[tlA*72 + f*4] = z;
                }
            }
        }
        // stage B from mt (already bf16, [d][s] layout)
        #pragma unroll
        for (int r = 0; r < 2; r++){
            int c = tid + r*256;
            int row = c >> 3, off = c & 7;
            short8 v = *(const short8*)&mt[((size_t)(b*4+q)*DDIM + d0 + row)*TSZ + ss0 + off*8];
            *(short8*)&B_sm[row*72 + off*8] = v;
        }
        __syncthreads();
        #pragma unroll
        for (int k0 = 0; k0 < 64; k0 += 32){
            short8 a0 = *(short8*)&A_sm[(wm + ln)*72 + k0 + qd*8];
            short8 a1 = *(short8*)&A_sm[(wm + 16 + ln)*72 + k0 + qd*8];
            short8 b0 = *(short8*)&B_sm[(wn + ln)*72 + k0 + qd*8];
            short8 b1 = *(short8*)&B_sm[(wn + 16 + ln)*72 + k0 + qd*8];
            acc[0][0] = __builtin_amdgcn_mfma_f32_16x16x32_bf16(a0, b0, acc[0][0], 0,0,0);
            acc[0][1] = __builtin_amdgcn_mfma_f32_16x16x32_bf16(a0, b1, acc[0][1], 0,0,0);
            acc[1][0] = __builtin_amdgcn_mfma_f32_16x16x32_bf16(a1, b0, acc[1][0], 0,0,0);
            acc[1][1] = __builtin_amdgcn_mfma_f32_16x16x32_bf16(a1, b1, acc[1][1], 0,0,0);
        }
        __syncthreads();
    }
    // epilogue: + lw_b + Bc @ le_W
    float le[2][8], lwbv[2];
    #pragma unroll
    for (int ni = 0; ni < 2; ni++){
        int d = d0 + wn + ni*16 + ln;
        lwbv[ni] = lwb[d];
        #pragma unroll
        for (int j = 0; j < 8; j++) le[ni][j] = leW[j*DDIM + d];
    }
    #pragma unroll
    for (int mi = 0; mi < 2; mi++){
        #pragma unroll
        for (int r = 0; r < 4; r++){
            int t = t0 + wm + mi*16 + qd*4 + r;
            if (t < TMM){
                float4 b0 = *(const float4*)&ws[WS_BC + (b*TMM + t)*8];
                float4 b1 = *(const float4*)&ws[WS_BC + (b*TMM + t)*8 + 4];
                float bcv[8] = {b0.x,b0.y,b0.z,b0.w,b1.x,b1.y,b1.z,b1.w};
                #pragma unroll
                for (int ni = 0; ni < 2; ni++){
                    int d = d0 + wn + ni*16 + ln;
                    float a = acc[mi][ni][r] + lwbv[ni];
                    #pragma unroll
                    for (int j = 0; j < 8; j++) a += bcv[j]*le[ni][j];
                    ws[WS_UP + ((size_t)b*TMM + t)*DDIM + d] = a;
                }
            }
        }
    }
}

// ---------------- K5: fused LayerNorm + MFMA GEMM (up_ln @ po_W) + mel-mask ----------------
__global__ __launch_bounds__(256) void k5_out(const float* __restrict__ lng,
                                              const float* __restrict__ lnb,
                                              const float* __restrict__ poW,
                                              const float* __restrict__ ws,
                                              float* __restrict__ out){
    int b = blockIdx.z;
    int t0 = blockIdx.x * 64;
    int n0 = blockIdx.y * 64;
    int mel = ((const int*)(ws + WS_ML))[b];
    __shared__ short A_sm[64*200];   // [t_local][k], pad 200
    __shared__ short B_sm[64*200];   // [n_local][k]
    int tid = threadIdx.x;
    // ---- stage A with fused LayerNorm: 4 threads per row, 48 floats each ----
    {
        int row = tid >> 2, part = tid & 3;
        int t = t0 + row;
        float x[48];
        if (t < TMM){
            const float* src = &ws[WS_UP + ((size_t)b*TMM + t)*DDIM + part*48];
            #pragma unroll
            for (int j = 0; j < 12; j++){
                float4 v = *(const float4*)&src[j*4];
                x[j*4+0] = v.x; x[j*4+1] = v.y; x[j*4+2] = v.z; x[j*4+3] = v.w;
            }
        } else {
            #pragma unroll
            for (int j = 0; j < 48; j++) x[j] = 0.f;
        }
        float s = 0.f, sq = 0.f;
        #pragma unroll
        for (int j = 0; j < 48; j++){ s += x[j]; sq += x[j]*x[j]; }
        s  += __shfl_xor(s, 1, 64);  s  += __shfl_xor(s, 2, 64);
        sq += __shfl_xor(sq, 1, 64); sq += __shfl_xor(sq, 2, 64);
        float m = s * (1.f/DDIM);
        float var = sq * (1.f/DDIM) - m*m;
        float rstd = rsqrtf(var + 1e-5f);
        #pragma unroll
        for (int j = 0; j < 48; j++){
            int k = part*48 + j;
            float a = (x[j] - m) * rstd * lng[k] + lnb[k];
            A_sm[row*200 + k] = f2bf(a);
        }
    }
    // ---- stage B: B_sm[n_local][k] = bf16(poW[k*384 + n0 + n_local]) (transpose) ----
    for (int r = 0; r < 12; r++){
        int c = tid + r*256;
        int k = c >> 4, p = c & 15;
        float4 v = *(const float4*)&poW[(size_t)k*(2*DDIM) + n0 + p*4];
        B_sm[(p*4+0)*200 + k] = f2bf(v.x);
        B_sm[(p*4+1)*200 + k] = f2bf(v.y);
        B_sm[(p*4+2)*200 + k] = f2bf(v.z);
        B_sm[(p*4+3)*200 + k] = f2bf(v.w);
    }
    __syncthreads();
    int w = tid >> 6, lane = tid & 63;
    int wm = (w & 1)*32, wn = (w >> 1)*32;
    int ln = lane & 15, qd = lane >> 4;
    floatx4 acc[2][2] = {};
    #pragma unroll
    for (int k0 = 0; k0 < DDIM; k0 += 32){
        short8 a0 = *(short8*)&A_sm[(wm + ln)*200 + k0 + qd*8];
        short8 a1 = *(short8*)&A_sm[(wm + 16 + ln)*200 + k0 + qd*8];
        short8 b0 = *(short8*)&B_sm[(wn + ln)*200 + k0 + qd*8];
        short8 b1 = *(short8*)&B_sm[(wn + 16 + ln)*200 + k0 + qd*8];
        acc[0][0] = __builtin_amdgcn_mfma_f32_16x16x32_bf16(a0, b0, acc[0][0], 0,0,0);
        acc[0][1] = __builtin_amdgcn_mfma_f32_16x16x32_bf16(a0, b1, acc[0][1], 0,0,0);
        acc[1][0] = __builtin_amdgcn_mfma_f32_16x16x32_bf16(a1, b0, acc[1][0], 0,0,0);
        acc[1][1] = __builtin_amdgcn_mfma_f32_16x16x32_bf16(a1, b1, acc[1][1], 0,0,0);
    }
    #pragma unroll
    for (int mi = 0; mi < 2; mi++)
      #pragma unroll
      for (int r = 0; r < 4; r++){
        int t = t0 + wm + mi*16 + qd*4 + r;
        if (t < TMM){
            bool live = (t < mel);
            #pragma unroll
            for (int ni = 0; ni < 2; ni++){
                int n = n0 + wn + ni*16 + ln;
                out[OUT_OUT + ((size_t)b*TMM + t)*(2*DDIM) + n] = live ? acc[mi][ni][r] : 0.f;
            }
        }
      }
}

extern "C" void kernel_launch(void* const* d_in, const int* in_sizes, int n_in,
                              void* d_out, int out_size, void* d_ws, size_t ws_size,
                              hipStream_t stream){
    const float* duration  = (const float*)d_in[0];
    const float* tokens    = (const float*)d_in[1];
    const int*   src_len   = (const int*)d_in[2];
    const float* cw_kernel = (const float*)d_in[6];
    const float* cw_bias   = (const float*)d_in[7];
    const float* cw_bng    = (const float*)d_in[8];
    const float* cw_bnb    = (const float*)d_in[9];
    const float* cw_bnm    = (const float*)d_in[10];
    const float* cw_bnv    = (const float*)d_in[11];
    const float* cw_lng    = (const float*)d_in[12];
    const float* cw_lnb    = (const float*)d_in[13];
    const float* sw_W1     = (const float*)d_in[14];
    const float* sw_b1     = (const float*)d_in[15];
    const float* sw_W2     = (const float*)d_in[16];
    const float* sw_b2     = (const float*)d_in[17];
    const float* sw_W3     = (const float*)d_in[18];
    const float* sw_b3     = (const float*)d_in[19];
    const float* lw_W      = (const float*)d_in[20];
    const float* lw_b      = (const float*)d_in[21];
    const float* cc_kernel = (const float*)d_in[22];
    const float* cc_bias   = (const float*)d_in[23];
    const float* cc_bng    = (const float*)d_in[24];
    const float* cc_bnb    = (const float*)d_in[25];
    const float* cc_bnm    = (const float*)d_in[26];
    const float* cc_bnv    = (const float*)d_in[27];
    const float* cc_lng    = (const float*)d_in[28];
    const float* cc_lnb    = (const float*)d_in[29];
    const float* sc_W1     = (const float*)d_in[30];
    const float* sc_b1     = (const float*)d_in[31];
    const float* sc_W2     = (const float*)d_in[32];
    const float* sc_b2     = (const float*)d_in[33];
    const float* sc_W3     = (const float*)d_in[34];
    const float* sc_b3     = (const float*)d_in[35];
    const float* le_W      = (const float*)d_in[36];
    const float* ln_gamma  = (const float*)d_in[37];
    const float* ln_beta   = (const float*)d_in[38];
    const float* po_W      = (const float*)d_in[39];
    float* out = (float*)d_out;
    float* ws  = (float*)d_ws;

    k0_scan<<<NB, TSZ, 0, stream>>>(duration, ws, out);
    k1_conv<<<dim3(16, NB), 512, 0, stream>>>(tokens,
        cw_kernel, cw_bias, cw_bng, cw_bnb, cw_bnm, cw_bnv, cw_lng, cw_lnb,
        cc_kernel, cc_bias, cc_bng, cc_bnb, cc_bnm, cc_bnv, cc_lng, cc_lnb,
        sw_W1, sw_b1, sc_W1, sc_b1, ws);
    k2_swish<<<dim3(250, NB), 256, 0, stream>>>(src_len,
        sw_W1, sw_W2, sw_b2, sw_W3, sw_b3,
        sc_W1, sc_W2, sc_b2, sc_W3, sc_b3, ws, out);
    k3_mgemm<<<dim3(8, 12, NB), 256, 0, stream>>>(tokens, lw_W, ws);
    k4_upgemm<<<dim3(16, 3, NB), 256, 0, stream>>>(out, lw_b, le_W, ws);
    k5_out<<<dim3(16, 6, NB), 256, 0, stream>>>(ln_gamma, ln_beta, po_W, ws, out);
}